// Round 3
// baseline (10045.918 us; speedup 1.0000x reference)
//
#include <hip/hip_runtime.h>
#include <stdint.h>

typedef _Float16 f16;
typedef f16 v8h __attribute__((ext_vector_type(8)));
typedef f16 v4h __attribute__((ext_vector_type(4)));
typedef f16 v2h __attribute__((ext_vector_type(2)));
typedef float v4f __attribute__((ext_vector_type(4)));

#define B_   64
#define L_   49
#define ENC_ 2048
#define D_   512
#define V_   10000
#define VP_  10048
#define T_   60
#define TM_  59
#define KS_  8   // split-K for LSTM gates GEMM
#define NBLK 256

__device__ __forceinline__ float sigmoidf_(float x) { return 1.f / (1.f + __expf(-x)); }
__device__ __forceinline__ float tanhf_(float x) {
  float e2 = __expf(2.f * x);
  return 1.f - 2.f / (e2 + 1.f);
}

// hand-rolled grid barrier (graph-capture-safe; no cooperative runtime).
// release-add then acquire-spin: agent scope => L2 wb/inv on gfx950 handles XCD non-coherence.
__device__ __forceinline__ void gsync(unsigned* bar, unsigned target) {
  __syncthreads();
  if (threadIdx.x == 0) {
    __hip_atomic_fetch_add(bar, 1u, __ATOMIC_RELEASE, __HIP_MEMORY_SCOPE_AGENT);
    while (__hip_atomic_load(bar, __ATOMIC_ACQUIRE, __HIP_MEMORY_SCOPE_AGENT) < target) {
      __builtin_amdgcn_s_sleep(1);
    }
  }
  __syncthreads();
}

// ---------------- one-shot f32 -> f16 casts (8 arrays) ----------------
struct CastJobs { const float* s[8]; f16* d[8]; int n4[8]; };
__global__ __launch_bounds__(256) void k_cast(CastJobs J) {
  int a = blockIdx.y;
  int i = blockIdx.x * 256 + threadIdx.x;
  if (i >= J.n4[a]) return;
  float4 v = ((const float4*)J.s[a])[i];
  v4h o; o[0] = (f16)v.x; o[1] = (f16)v.y; o[2] = (f16)v.z; o[3] = (f16)v.w;
  ((v4h*)J.d[a])[i] = o;
}

// fc_w cast with pad to 10048 columns (zero fill)
__global__ __launch_bounds__(256) void k_castpad(const float* __restrict__ s,
                                                 f16* __restrict__ d) {
  int r = blockIdx.y;
  int c4 = blockIdx.x * 256 + threadIdx.x;
  if (c4 >= VP_ / 4) return;
  int c = c4 * 4;
  v4h o;
  if (c + 3 < V_) {
    float4 v = *(const float4*)(s + (size_t)r * V_ + c);
    o[0] = (f16)v.x; o[1] = (f16)v.y; o[2] = (f16)v.z; o[3] = (f16)v.w;
  } else {
    #pragma unroll
    for (int j = 0; j < 4; j++)
      o[j] = (c + j < V_) ? (f16)s[(size_t)r * V_ + c + j] : (f16)0.f;
  }
  *(v4h*)(d + (size_t)r * VP_ + c) = o;
}

// ---------------- mean over L (also zeroes the grid barrier) ----------------
__global__ __launch_bounds__(256) void k_mean(const f16* __restrict__ inh,
                                              f16* __restrict__ meanh,
                                              unsigned* __restrict__ bar) {
  int b = blockIdx.x, tid = threadIdx.x;
  if (b == 0 && tid == 0)
    __hip_atomic_store(bar, 0u, __ATOMIC_RELEASE, __HIP_MEMORY_SCOPE_AGENT);
  for (int e = tid; e < ENC_; e += 256) {
    float s = 0.f;
    for (int l = 0; l < L_; l++) s += (float)inh[((size_t)(b * L_ + l)) * ENC_ + e];
    meanh[b * ENC_ + e] = (f16)(s * (1.f / 49.f));
  }
}

// ---------------- emb gather (all steps) ----------------
__global__ __launch_bounds__(128) void k_embgather(const int* __restrict__ captions,
    const float* __restrict__ embw, f16* __restrict__ emball) {
  int row = blockIdx.x;           // t*64 + b
  int t = row >> 6, b = row & 63;
  int cap = captions[b * T_ + t];
  int k = threadIdx.x * 4;
  float4 v = *(const float4*)(embw + (size_t)cap * 512 + k);
  v4h o; o[0] = (f16)v.x; o[1] = (f16)v.y; o[2] = (f16)v.z; o[3] = (f16)v.w;
  *(v4h*)(emball + (size_t)row * 512 + k) = o;
}

// ---------------- shared 64x64 f16 MFMA tile helpers ----------------
struct AR { uint4 x, y; };
struct BR { v4h b[4]; };

__device__ __forceinline__ AR load_a64(const f16* src, int lda, int tid) {
  int r = tid >> 2, k = (tid & 3) << 4;
  const f16* p = src + (size_t)r * lda + k;
  AR a; a.x = *(const uint4*)p; a.y = *(const uint4*)(p + 8); return a;
}
__device__ __forceinline__ void write_a64(const AR& a, f16 (*sA)[72], int tid) {
  int r = tid >> 2, k = (tid & 3) << 4;
  *(uint4*)&sA[r][k] = a.x; *(uint4*)&sA[r][k + 8] = a.y;
}
__device__ __forceinline__ BR load_b64(const f16* src, int ldb, int tid) {
  BR b;
  #pragma unroll
  for (int s = 0; s < 4; s++) {
    int slot = tid + s * 256;
    int kr = slot >> 4, nc = (slot & 15) << 2;
    b.b[s] = *(const v4h*)(src + (size_t)kr * ldb + nc);
  }
  return b;
}
__device__ __forceinline__ void write_b64(const BR& b, f16 (*sB)[72], int tid) {
  #pragma unroll
  for (int s = 0; s < 4; s++) {
    int slot = tid + s * 256;
    int kr = slot >> 4, nc = (slot & 15) << 2;
    sB[nc + 0][kr] = b.b[s][0]; sB[nc + 1][kr] = b.b[s][1];
    sB[nc + 2][kr] = b.b[s][2]; sB[nc + 3][kr] = b.b[s][3];
  }
}
__device__ __forceinline__ void mfma_tile(const f16 (*sA)[72], const f16 (*sB)[72],
                                          int fr, int fq, int wv, v4f* acc) {
  #pragma unroll
  for (int kk = 0; kk < 64; kk += 32) {
    v8h bfr = *(const v8h*)&sB[wv * 16 + fr][kk + fq * 8];
    #pragma unroll
    for (int mt = 0; mt < 4; mt++) {
      v8h afr = *(const v8h*)&sA[mt * 16 + fr][kk + fq * 8];
      acc[mt] = __builtin_amdgcn_mfma_f32_16x16x32_f16(afr, bfr, acc[mt], 0, 0, 0);
    }
  }
}

// double-buffered K loop
template <typename F>
__device__ __forceinline__ void gemm_db(int nch, F srcf,
    f16 (*sA)[64][72], f16 (*sB)[64][72],
    int tid, int fr, int fq, int wv, v4f* acc) {
  const f16 *ap, *bp; int la, lb;
  srcf(0, ap, la, bp, lb);
  AR ar = load_a64(ap, la, tid);
  BR br = load_b64(bp, lb, tid);
  int cur = 0;
  for (int ch = 0; ch < nch; ch++) {
    AR an = ar; BR bn = br;
    if (ch + 1 < nch) {
      srcf(ch + 1, ap, la, bp, lb);
      an = load_a64(ap, la, tid);
      bn = load_b64(bp, lb, tid);
    }
    write_a64(ar, sA[cur], tid);
    write_b64(br, sB[cur], tid);
    __syncthreads();
    mfma_tile(sA[cur], sB[cur], fr, fq, wv, acc);
    ar = an; br = bn; cur ^= 1;
  }
}

// ---------------- h0/c0 ----------------
__global__ __launch_bounds__(256) void k_h0c0(const f16* __restrict__ meanh,
    const f16* __restrict__ hw, const float* __restrict__ hb,
    const f16* __restrict__ cw, const float* __restrict__ cb,
    float* __restrict__ h, float* __restrict__ c, f16* __restrict__ hh) {
  __shared__ __align__(16) f16 sA[2][64][72], sB[2][64][72];
  int tid = threadIdx.x, lane = tid & 63, wv = tid >> 6, fr = lane & 15, fq = lane >> 4;
  int n0 = blockIdx.x * 64;
  bool ish = n0 < 512;
  const f16* W = ish ? hw : cw;
  const float* bb = ish ? hb : cb;
  int nb = ish ? n0 : (n0 - 512);
  v4f acc[4] = {};
  auto src = [&](int ch, const f16*& ap, int& la, const f16*& bp, int& lb) {
    ap = meanh + ch * 64; la = ENC_;
    bp = W + (size_t)(ch * 64) * 512 + nb; lb = 512;
  };
  gemm_db(32, src, sA, sB, tid, fr, fq, wv, acc);
  int col = nb + wv * 16 + fr;
  float bv = bb[col];
  #pragma unroll
  for (int mt = 0; mt < 4; mt++)
    #pragma unroll
    for (int r = 0; r < 4; r++) {
      int b = mt * 16 + fq * 4 + r;
      float v = acc[mt][r] + bv;
      if (ish) { h[b * 512 + col] = v; hh[b * 512 + col] = (f16)v; }
      else       c[b * 512 + col] = v;
    }
}

// ---------------- enc_proj ----------------
__global__ __launch_bounds__(256) void k_ep(const f16* __restrict__ inh,
    const f16* __restrict__ Wh, const float* __restrict__ bias,
    float* __restrict__ out) {
  __shared__ __align__(16) f16 sA[2][64][72], sB[2][64][72];
  int tid = threadIdx.x, lane = tid & 63, wv = tid >> 6, fr = lane & 15, fq = lane >> 4;
  int m0 = blockIdx.x * 64, n0 = blockIdx.y * 64;
  v4f acc[4] = {};
  auto src = [&](int ch, const f16*& ap, int& la, const f16*& bp, int& lb) {
    ap = inh + (size_t)m0 * ENC_ + ch * 64; la = ENC_;
    bp = Wh + (size_t)(ch * 64) * 512 + n0; lb = 512;
  };
  gemm_db(32, src, sA, sB, tid, fr, fq, wv, acc);
  int col = n0 + wv * 16 + fr;
  float bv = bias[col];
  #pragma unroll
  for (int mt = 0; mt < 4; mt++)
    #pragma unroll
    for (int r = 0; r < 4; r++)
      out[(size_t)(m0 + mt * 16 + fq * 4 + r) * 512 + col] = acc[mt][r] + bv;
}

// ---------------- embproj = emball @ wih[0:512] + bih + bhh ----------------
__global__ __launch_bounds__(256) void k_embproj(const f16* __restrict__ emball,
    const f16* __restrict__ wih, const float* __restrict__ bih,
    const float* __restrict__ bhh, float* __restrict__ out) {
  __shared__ __align__(16) f16 sA[2][64][72], sB[2][64][72];
  int tid = threadIdx.x, lane = tid & 63, wv = tid >> 6, fr = lane & 15, fq = lane >> 4;
  int m0 = blockIdx.x * 64, n0 = blockIdx.y * 64;
  v4f acc[4] = {};
  auto src = [&](int ch, const f16*& ap, int& la, const f16*& bp, int& lb) {
    ap = emball + (size_t)m0 * 512 + ch * 64; la = 512;
    bp = wih + (size_t)(ch * 64) * 2048 + n0; lb = 2048;
  };
  gemm_db(8, src, sA, sB, tid, fr, fq, wv, acc);
  int col = n0 + wv * 16 + fr;
  float bv = bih[col] + bhh[col];
  #pragma unroll
  for (int mt = 0; mt < 4; mt++)
    #pragma unroll
    for (int r = 0; r < 4; r++)
      out[(size_t)(m0 + mt * 16 + fq * 4 + r) * 2048 + col] = acc[mt][r] + bv;
}

// ---------------- persistent time-loop kernel (hand-rolled grid barrier) ----------------
struct LP {
  const f16* inh; const float* encproj; const float* att_w; const float* att_b;
  const f16* daw; const float* bd; const f16* avw; const float* ba;
  const f16* whh; const f16* wih2; const float* embpj; const int* lens;
  float* aout;   // [2][64][4608] split-K partials of h @ [Wd|Wa|whh]
  f16* xg; float* part;
  float* h; float* c; f16* hh; f16* hseq; float* probs;
  unsigned* bar;
};

__global__ __launch_bounds__(256) void k_loop(LP P) {
  __shared__ __align__(16) char smem[4 * 64 * 72 * 2];   // 36864 B
  f16 (*sA)[64][72] = (f16(*)[64][72])smem;
  f16 (*sB)[64][72] = (f16(*)[64][72])(smem + 2 * 64 * 72 * 2);
  int tid = threadIdx.x, lane = tid & 63, wv = tid >> 6;
  int fr = lane & 15, fq = lane >> 4;
  int blk = blockIdx.x;
  unsigned bno = 0;

  for (int t = 0; t < TM_; t++) {
    // ---- Phase A: h @ [Wd | Wa | whh], split-K=2 ----
    if (blk < 144) {
      int z = (blk >= 72) ? 1 : 0, nt = blk - z * 72;
      int n0 = nt * 64;
      const f16* W; int ldb, bo;
      if (n0 < 512)       { W = P.daw; ldb = 512;  bo = n0; }
      else if (n0 < 2560) { W = P.avw; ldb = 2048; bo = n0 - 512; }
      else                { W = P.whh; ldb = 2048; bo = n0 - 2560; }
      v4f acc[4] = {};
      auto src = [&](int ch, const f16*& ap, int& la, const f16*& bp, int& lb) {
        int kl = z * 256 + ch * 64;
        ap = P.hh + kl; la = 512;
        bp = W + (size_t)kl * ldb + bo; lb = ldb;
      };
      gemm_db(4, src, sA, sB, tid, fr, fq, wv, acc);
      float* ao = P.aout + (size_t)z * 64 * 4608;
      int col = n0 + wv * 16 + fr;
      #pragma unroll
      for (int mt = 0; mt < 4; mt++)
        #pragma unroll
        for (int r = 0; r < 4; r++) {
          int b = mt * 16 + fq * 4 + r;
          ao[(size_t)b * 4608 + col] = acc[mt][r];
        }
    }
    gsync(P.bar, (++bno) * NBLK);

    // ---- Phase B: attention + xg (4 blocks per batch) ----
    {
      float* sd = (float*)smem;
      float* sw = sd + 512;
      float* ss = sw + 512;
      float* sp = ss + 64;
      int b = blk >> 2, q = blk & 3;
      const float* a0 = P.aout + (size_t)b * 4608;
      const float* a1 = a0 + (size_t)64 * 4608;
      for (int i = tid; i < 512; i += 256) {
        sd[i] = a0[i] + a1[i] + P.bd[i];
        sw[i] = P.att_w[i];
      }
      __syncthreads();
      for (int l = wv; l < L_; l += 4) {
        const float* ep = P.encproj + ((size_t)(b * L_ + l)) * 512;
        float p = 0.f;
        #pragma unroll
        for (int j = 0; j < 8; j++) {
          int A0 = lane + j * 64;
          float v = ep[A0] + sd[A0];
          p = fmaf(fmaxf(v, 0.f), sw[A0], p);
        }
        #pragma unroll
        for (int off = 32; off > 0; off >>= 1) p += __shfl_xor(p, off);
        if (lane == 0) ss[l] = p;
      }
      __syncthreads();
      if (wv == 0) {
        float v = (lane < L_) ? (ss[lane] + P.att_b[0]) : -3.0e38f;
        float m = v;
        #pragma unroll
        for (int off = 32; off > 0; off >>= 1) m = fmaxf(m, __shfl_xor(m, off));
        float e = (lane < L_) ? __expf(v - m) : 0.f;
        float s = e;
        #pragma unroll
        for (int off = 32; off > 0; off >>= 1) s += __shfl_xor(s, off);
        float pr = e / s;
        if (lane < L_) {
          sp[lane] = pr;
          if (q == 0) {
            bool act = t < (P.lens[b] - 1);
            P.probs[((size_t)b * TM_ + t) * L_ + lane] = act ? pr : 0.f;
          }
        }
      }
      __syncthreads();
      int e = q * 512 + tid * 2;
      const f16* ip = P.inh + (size_t)b * L_ * ENC_ + e;
      float av0 = 0.f, av1 = 0.f;
      for (int l = 0; l < L_; l++) {
        v2h x = *(const v2h*)(ip + (size_t)l * ENC_);
        float pl = sp[l];
        av0 = fmaf(pl, (float)x[0], av0);
        av1 = fmaf(pl, (float)x[1], av1);
      }
      float g0 = sigmoidf_(a0[512 + e]     + a1[512 + e]     + P.ba[e]);
      float g1 = sigmoidf_(a0[512 + e + 1] + a1[512 + e + 1] + P.ba[e + 1]);
      v2h o; o[0] = (f16)(av0 * g0); o[1] = (f16)(av1 * g1);
      *(v2h*)(P.xg + (size_t)b * 2048 + e) = o;
    }
    gsync(P.bar, (++bno) * NBLK);

    // ---- Phase C: xg @ wih[512:2560], split-K=8 ----
    {
      int n0 = (blk & 31) * 64, z = blk >> 5;
      v4f acc[4] = {};
      auto src = [&](int ch, const f16*& ap, int& la, const f16*& bp, int& lb) {
        int kl = z * 256 + ch * 64;
        ap = P.xg + kl; la = 2048;
        bp = P.wih2 + (size_t)kl * 2048 + n0; lb = 2048;
      };
      gemm_db(4, src, sA, sB, tid, fr, fq, wv, acc);
      int col = n0 + wv * 16 + fr;
      float* pp = P.part + ((size_t)z * 64) * 2048;
      #pragma unroll
      for (int mt = 0; mt < 4; mt++)
        #pragma unroll
        for (int r = 0; r < 4; r++) {
          int b = mt * 16 + fq * 4 + r;
          pp[(size_t)b * 2048 + col] = acc[mt][r];
        }
    }
    gsync(P.bar, (++bno) * NBLK);

    // ---- Phase D: reduce + LSTM cell ----
    if (blk < 128) {
      int b = blk >> 1;
      int d = (blk & 1) * 256 + tid;
      const float* a0 = P.aout + (size_t)b * 4608 + 2560;
      const float* a1 = a0 + (size_t)64 * 4608;
      float g[4];
      #pragma unroll
      for (int qq = 0; qq < 4; qq++) {
        int n = qq * 512 + d;
        float s = P.embpj[((size_t)(t * 64 + b)) * 2048 + n] + a0[n] + a1[n];
        #pragma unroll
        for (int z = 0; z < KS_; z++) s += P.part[((size_t)(z * 64 + b)) * 2048 + n];
        g[qq] = s;
      }
      float i_ = sigmoidf_(g[0]);
      float f_ = sigmoidf_(g[1]);
      float gg = tanhf_(g[2]);
      float o_ = sigmoidf_(g[3]);
      float cold = P.c[b * 512 + d], hold = P.h[b * 512 + d];
      float cn = f_ * cold + i_ * gg;
      float hn = o_ * tanhf_(cn);
      bool act = t < (P.lens[b] - 1);
      float ho = act ? hn : hold;
      float co = act ? cn : cold;
      P.h[b * 512 + d] = ho;
      P.c[b * 512 + d] = co;
      P.hh[b * 512 + d] = (f16)ho;
      P.hseq[((size_t)t * 64 + b) * 512 + d] = (f16)ho;
    }
    gsync(P.bar, (++bno) * NBLK);
  }
}

// ---------------- final: preds = hseq @ fc_w + fc_b ----------------
__global__ __launch_bounds__(256) void k_fc(const f16* __restrict__ hseq,
    const f16* __restrict__ W, const float* __restrict__ bias,
    const int* __restrict__ lens, float* __restrict__ preds) {
  __shared__ __align__(16) f16 sA[2][64][72], sB[2][64][72];
  int tid = threadIdx.x, lane = tid & 63, wv = tid >> 6, fr = lane & 15, fq = lane >> 4;
  int t = blockIdx.x, n0 = blockIdx.y * 64;
  v4f acc[4] = {};
  auto src = [&](int ch, const f16*& ap, int& la, const f16*& bp, int& lb) {
    ap = hseq + ((size_t)t * 64) * 512 + ch * 64; la = 512;
    bp = W + (size_t)(ch * 64) * VP_ + n0; lb = VP_;
  };
  gemm_db(8, src, sA, sB, tid, fr, fq, wv, acc);
  int col = n0 + wv * 16 + fr;
  if (col < V_) {
    float bv = bias[col];
    #pragma unroll
    for (int mt = 0; mt < 4; mt++)
      #pragma unroll
      for (int r = 0; r < 4; r++) {
        int b = mt * 16 + fq * 4 + r;
        bool act = t < (lens[b] - 1);
        preds[((size_t)b * TM_ + t) * (size_t)V_ + col] = act ? (acc[mt][r] + bv) : 0.f;
      }
  }
}

extern "C" void kernel_launch(void* const* d_in, const int* in_sizes, int n_in,
                              void* d_out, int out_size, void* d_ws, size_t ws_size,
                              hipStream_t stream) {
  (void)in_sizes; (void)n_in; (void)out_size; (void)ws_size;
  const float* input     = (const float*)d_in[0];
  const int*   captions  = (const int*)d_in[1];
  const int*   lens      = (const int*)d_in[2];
  const float* embw      = (const float*)d_in[3];
  const float* enc_att_w = (const float*)d_in[4];
  const float* enc_att_b = (const float*)d_in[5];
  const float* dec_att_w = (const float*)d_in[6];
  const float* dec_att_b = (const float*)d_in[7];
  const float* att_w     = (const float*)d_in[8];
  const float* att_b     = (const float*)d_in[9];
  const float* h_w       = (const float*)d_in[10];
  const float* h_b       = (const float*)d_in[11];
  const float* c_w       = (const float*)d_in[12];
  const float* c_b       = (const float*)d_in[13];
  const float* actv_w    = (const float*)d_in[14];
  const float* actv_b    = (const float*)d_in[15];
  const float* wih       = (const float*)d_in[16];
  const float* whh       = (const float*)d_in[17];
  const float* bih       = (const float*)d_in[18];
  const float* bhh       = (const float*)d_in[19];
  const float* fc_w      = (const float*)d_in[20];
  const float* fc_b      = (const float*)d_in[21];

  float* preds = (float*)d_out;
  float* probs = preds + (size_t)B_ * TM_ * V_;

  char* w = (char*)d_ws;
  auto alloc = [&](size_t bytes) -> char* {
    char* p = w; w += (bytes + 255) & ~(size_t)255; return p;
  };
  f16* input_h = (f16*)alloc((size_t)6422528 * 2);
  f16* eaw_h   = (f16*)alloc((size_t)1048576 * 2);
  f16* daw_h   = (f16*)alloc((size_t)262144 * 2);
  f16* avw_h   = (f16*)alloc((size_t)1048576 * 2);
  f16* wih_h   = (f16*)alloc((size_t)5242880 * 2);
  f16* whh_h   = (f16*)alloc((size_t)1048576 * 2);
  f16* hw_h    = (f16*)alloc((size_t)1048576 * 2);
  f16* cw_h    = (f16*)alloc((size_t)1048576 * 2);
  f16* fcw_pad = (f16*)alloc((size_t)512 * VP_ * 2);
  f16* meanh   = (f16*)alloc((size_t)B_ * ENC_ * 2);
  float* encproj = (float*)alloc((size_t)3136 * 512 * 4);
  float* hbuf  = (float*)alloc((size_t)B_ * 512 * 4);
  float* cbuf  = (float*)alloc((size_t)B_ * 512 * 4);
  f16*   hh    = (f16*)alloc((size_t)B_ * 512 * 2);
  float* aout  = (float*)alloc((size_t)2 * 64 * 4608 * 4);
  f16*   xg    = (f16*)alloc((size_t)B_ * 2048 * 2);
  float* part  = (float*)alloc((size_t)KS_ * B_ * 2048 * 4);
  f16*   hseq  = (f16*)alloc((size_t)TM_ * B_ * 512 * 2);
  f16*   embal = (f16*)alloc((size_t)TM_ * B_ * 512 * 2);
  float* embpj = (float*)alloc((size_t)TM_ * B_ * 2048 * 4);
  unsigned* bar = (unsigned*)alloc(256);

  CastJobs J;
  J.s[0] = input;     J.d[0] = input_h; J.n4[0] = 6422528 / 4;
  J.s[1] = enc_att_w; J.d[1] = eaw_h;   J.n4[1] = 1048576 / 4;
  J.s[2] = dec_att_w; J.d[2] = daw_h;   J.n4[2] = 262144 / 4;
  J.s[3] = actv_w;    J.d[3] = avw_h;   J.n4[3] = 1048576 / 4;
  J.s[4] = wih;       J.d[4] = wih_h;   J.n4[4] = 5242880 / 4;
  J.s[5] = whh;       J.d[5] = whh_h;   J.n4[5] = 1048576 / 4;
  J.s[6] = h_w;       J.d[6] = hw_h;    J.n4[6] = 1048576 / 4;
  J.s[7] = c_w;       J.d[7] = cw_h;    J.n4[7] = 1048576 / 4;
  k_cast<<<dim3((1605632 + 255) / 256, 8), 256, 0, stream>>>(J);
  k_castpad<<<dim3((VP_ / 4 + 255) / 256, 512), 256, 0, stream>>>(fc_w, fcw_pad);

  k_mean<<<64, 256, 0, stream>>>(input_h, meanh, bar);
  k_embgather<<<TM_ * B_, 128, 0, stream>>>(captions, embw, embal);
  k_h0c0<<<16, 256, 0, stream>>>(meanh, hw_h, h_b, cw_h, c_b, hbuf, cbuf, hh);
  k_ep<<<dim3(49, 8), 256, 0, stream>>>(input_h, eaw_h, enc_att_b, encproj);
  k_embproj<<<dim3(TM_, 32), 256, 0, stream>>>(embal, wih_h, bih, bhh, embpj);

  LP P;
  P.inh = input_h; P.encproj = encproj; P.att_w = att_w; P.att_b = att_b;
  P.daw = daw_h; P.bd = dec_att_b; P.avw = avw_h; P.ba = actv_b;
  P.whh = whh_h; P.wih2 = wih_h + (size_t)512 * 2048;
  P.embpj = embpj; P.lens = lens;
  P.aout = aout; P.xg = xg; P.part = part;
  P.h = hbuf; P.c = cbuf; P.hh = hh; P.hseq = hseq; P.probs = probs;
  P.bar = bar;
  k_loop<<<NBLK, 256, 0, stream>>>(P);

  k_fc<<<dim3(59, 157), 256, 0, stream>>>(hseq, fcw_pad, fc_b, lens, preds);
}

// Round 4
// 6653.864 us; speedup vs baseline: 1.5098x; 1.5098x over previous
//
#include <hip/hip_runtime.h>
#include <stdint.h>

typedef _Float16 f16;
typedef f16 v8h __attribute__((ext_vector_type(8)));
typedef f16 v4h __attribute__((ext_vector_type(4)));
typedef f16 v2h __attribute__((ext_vector_type(2)));
typedef float v4f __attribute__((ext_vector_type(4)));

#define B_   64
#define L_   49
#define ENC_ 2048
#define D_   512
#define V_   10000
#define VP_  10048
#define T_   60
#define TM_  59
#define KS_  8   // split-K for LSTM gates GEMM
#define NBLK 256

__device__ __forceinline__ float sigmoidf_(float x) { return 1.f / (1.f + __expf(-x)); }
__device__ __forceinline__ float tanhf_(float x) {
  float e2 = __expf(2.f * x);
  return 1.f - 2.f / (e2 + 1.f);
}

// ---- two-level grid barrier: relaxed polls, ONE acquire fence per block ----
// arrive[blk]: per-block epoch slot (release store = wbl2 + sc1 store, once).
// block 0 aggregates with relaxed sc1 loads (no L2 invalidates), publishes go.
// Exit: single fence(acquire, agent) -> one buffer_inv per block per barrier.
__device__ __forceinline__ void gsync(unsigned* arrive, unsigned* go, unsigned epoch) {
  int tid = threadIdx.x, blk = blockIdx.x;
  __syncthreads();
  if (blk == 0) {
    if (tid > 0 && tid < NBLK) {
      while (__hip_atomic_load(&arrive[tid], __ATOMIC_RELAXED, __HIP_MEMORY_SCOPE_AGENT) < epoch)
        __builtin_amdgcn_s_sleep(1);
    }
    __syncthreads();
    if (tid == 0)
      __hip_atomic_store(go, epoch, __ATOMIC_RELEASE, __HIP_MEMORY_SCOPE_AGENT);
  } else {
    if (tid == 0) {
      __hip_atomic_store(&arrive[blk], epoch, __ATOMIC_RELEASE, __HIP_MEMORY_SCOPE_AGENT);
      while (__hip_atomic_load(go, __ATOMIC_RELAXED, __HIP_MEMORY_SCOPE_AGENT) < epoch)
        __builtin_amdgcn_s_sleep(1);
    }
  }
  __builtin_amdgcn_fence(__ATOMIC_ACQUIRE, "agent");
  __syncthreads();
}

// ---------------- one-shot f32 -> f16 casts (8 arrays) ----------------
struct CastJobs { const float* s[8]; f16* d[8]; int n4[8]; };
__global__ __launch_bounds__(256) void k_cast(CastJobs J) {
  int a = blockIdx.y;
  int i = blockIdx.x * 256 + threadIdx.x;
  if (i >= J.n4[a]) return;
  float4 v = ((const float4*)J.s[a])[i];
  v4h o; o[0] = (f16)v.x; o[1] = (f16)v.y; o[2] = (f16)v.z; o[3] = (f16)v.w;
  ((v4h*)J.d[a])[i] = o;
}

// fc_w cast with pad to 10048 columns (zero fill)
__global__ __launch_bounds__(256) void k_castpad(const float* __restrict__ s,
                                                 f16* __restrict__ d) {
  int r = blockIdx.y;
  int c4 = blockIdx.x * 256 + threadIdx.x;
  if (c4 >= VP_ / 4) return;
  int c = c4 * 4;
  v4h o;
  if (c + 3 < V_) {
    float4 v = *(const float4*)(s + (size_t)r * V_ + c);
    o[0] = (f16)v.x; o[1] = (f16)v.y; o[2] = (f16)v.z; o[3] = (f16)v.w;
  } else {
    #pragma unroll
    for (int j = 0; j < 4; j++)
      o[j] = (c + j < V_) ? (f16)s[(size_t)r * V_ + c + j] : (f16)0.f;
  }
  *(v4h*)(d + (size_t)r * VP_ + c) = o;
}

// ---------------- mean over L (also resets the grid barrier) ----------------
__global__ __launch_bounds__(256) void k_mean(const f16* __restrict__ inh,
                                              f16* __restrict__ meanh,
                                              unsigned* __restrict__ arrive,
                                              unsigned* __restrict__ go) {
  int b = blockIdx.x, tid = threadIdx.x;
  if (b == 0) {
    __hip_atomic_store(&arrive[tid], 0u, __ATOMIC_RELAXED, __HIP_MEMORY_SCOPE_AGENT);
    if (tid == 0)
      __hip_atomic_store(go, 0u, __ATOMIC_RELAXED, __HIP_MEMORY_SCOPE_AGENT);
  }
  for (int e = tid; e < ENC_; e += 256) {
    float s = 0.f;
    for (int l = 0; l < L_; l++) s += (float)inh[((size_t)(b * L_ + l)) * ENC_ + e];
    meanh[b * ENC_ + e] = (f16)(s * (1.f / 49.f));
  }
}

// ---------------- emb gather (all steps) ----------------
__global__ __launch_bounds__(128) void k_embgather(const int* __restrict__ captions,
    const float* __restrict__ embw, f16* __restrict__ emball) {
  int row = blockIdx.x;           // t*64 + b
  int t = row >> 6, b = row & 63;
  int cap = captions[b * T_ + t];
  int k = threadIdx.x * 4;
  float4 v = *(const float4*)(embw + (size_t)cap * 512 + k);
  v4h o; o[0] = (f16)v.x; o[1] = (f16)v.y; o[2] = (f16)v.z; o[3] = (f16)v.w;
  *(v4h*)(emball + (size_t)row * 512 + k) = o;
}

// ---------------- shared 64x64 f16 MFMA tile helpers ----------------
struct AR { uint4 x, y; };
struct BR { v4h b[4]; };

__device__ __forceinline__ AR load_a64(const f16* src, int lda, int tid) {
  int r = tid >> 2, k = (tid & 3) << 4;
  const f16* p = src + (size_t)r * lda + k;
  AR a; a.x = *(const uint4*)p; a.y = *(const uint4*)(p + 8); return a;
}
__device__ __forceinline__ void write_a64(const AR& a, f16 (*sA)[72], int tid) {
  int r = tid >> 2, k = (tid & 3) << 4;
  *(uint4*)&sA[r][k] = a.x; *(uint4*)&sA[r][k + 8] = a.y;
}
__device__ __forceinline__ BR load_b64(const f16* src, int ldb, int tid) {
  BR b;
  #pragma unroll
  for (int s = 0; s < 4; s++) {
    int slot = tid + s * 256;
    int kr = slot >> 4, nc = (slot & 15) << 2;
    b.b[s] = *(const v4h*)(src + (size_t)kr * ldb + nc);
  }
  return b;
}
__device__ __forceinline__ void write_b64(const BR& b, f16 (*sB)[72], int tid) {
  #pragma unroll
  for (int s = 0; s < 4; s++) {
    int slot = tid + s * 256;
    int kr = slot >> 4, nc = (slot & 15) << 2;
    sB[nc + 0][kr] = b.b[s][0]; sB[nc + 1][kr] = b.b[s][1];
    sB[nc + 2][kr] = b.b[s][2]; sB[nc + 3][kr] = b.b[s][3];
  }
}
__device__ __forceinline__ void mfma_tile(const f16 (*sA)[72], const f16 (*sB)[72],
                                          int fr, int fq, int wv, v4f* acc) {
  #pragma unroll
  for (int kk = 0; kk < 64; kk += 32) {
    v8h bfr = *(const v8h*)&sB[wv * 16 + fr][kk + fq * 8];
    #pragma unroll
    for (int mt = 0; mt < 4; mt++) {
      v8h afr = *(const v8h*)&sA[mt * 16 + fr][kk + fq * 8];
      acc[mt] = __builtin_amdgcn_mfma_f32_16x16x32_f16(afr, bfr, acc[mt], 0, 0, 0);
    }
  }
}

// double-buffered K loop
template <typename F>
__device__ __forceinline__ void gemm_db(int nch, F srcf,
    f16 (*sA)[64][72], f16 (*sB)[64][72],
    int tid, int fr, int fq, int wv, v4f* acc) {
  const f16 *ap, *bp; int la, lb;
  srcf(0, ap, la, bp, lb);
  AR ar = load_a64(ap, la, tid);
  BR br = load_b64(bp, lb, tid);
  int cur = 0;
  for (int ch = 0; ch < nch; ch++) {
    AR an = ar; BR bn = br;
    if (ch + 1 < nch) {
      srcf(ch + 1, ap, la, bp, lb);
      an = load_a64(ap, la, tid);
      bn = load_b64(bp, lb, tid);
    }
    write_a64(ar, sA[cur], tid);
    write_b64(br, sB[cur], tid);
    __syncthreads();
    mfma_tile(sA[cur], sB[cur], fr, fq, wv, acc);
    ar = an; br = bn; cur ^= 1;
  }
}

// ---------------- h0/c0 ----------------
__global__ __launch_bounds__(256) void k_h0c0(const f16* __restrict__ meanh,
    const f16* __restrict__ hw, const float* __restrict__ hb,
    const f16* __restrict__ cw, const float* __restrict__ cb,
    float* __restrict__ h, float* __restrict__ c, f16* __restrict__ hh) {
  __shared__ __align__(16) f16 sA[2][64][72], sB[2][64][72];
  int tid = threadIdx.x, lane = tid & 63, wv = tid >> 6, fr = lane & 15, fq = lane >> 4;
  int n0 = blockIdx.x * 64;
  bool ish = n0 < 512;
  const f16* W = ish ? hw : cw;
  const float* bb = ish ? hb : cb;
  int nb = ish ? n0 : (n0 - 512);
  v4f acc[4] = {};
  auto src = [&](int ch, const f16*& ap, int& la, const f16*& bp, int& lb) {
    ap = meanh + ch * 64; la = ENC_;
    bp = W + (size_t)(ch * 64) * 512 + nb; lb = 512;
  };
  gemm_db(32, src, sA, sB, tid, fr, fq, wv, acc);
  int col = nb + wv * 16 + fr;
  float bv = bb[col];
  #pragma unroll
  for (int mt = 0; mt < 4; mt++)
    #pragma unroll
    for (int r = 0; r < 4; r++) {
      int b = mt * 16 + fq * 4 + r;
      float v = acc[mt][r] + bv;
      if (ish) { h[b * 512 + col] = v; hh[b * 512 + col] = (f16)v; }
      else       c[b * 512 + col] = v;
    }
}

// ---------------- enc_proj (f16 output) ----------------
__global__ __launch_bounds__(256) void k_ep(const f16* __restrict__ inh,
    const f16* __restrict__ Wh, const float* __restrict__ bias,
    f16* __restrict__ out) {
  __shared__ __align__(16) f16 sA[2][64][72], sB[2][64][72];
  int tid = threadIdx.x, lane = tid & 63, wv = tid >> 6, fr = lane & 15, fq = lane >> 4;
  int m0 = blockIdx.x * 64, n0 = blockIdx.y * 64;
  v4f acc[4] = {};
  auto src = [&](int ch, const f16*& ap, int& la, const f16*& bp, int& lb) {
    ap = inh + (size_t)m0 * ENC_ + ch * 64; la = ENC_;
    bp = Wh + (size_t)(ch * 64) * 512 + n0; lb = 512;
  };
  gemm_db(32, src, sA, sB, tid, fr, fq, wv, acc);
  int col = n0 + wv * 16 + fr;
  float bv = bias[col];
  #pragma unroll
  for (int mt = 0; mt < 4; mt++)
    #pragma unroll
    for (int r = 0; r < 4; r++)
      out[(size_t)(m0 + mt * 16 + fq * 4 + r) * 512 + col] = (f16)(acc[mt][r] + bv);
}

// ---------------- embproj = emball @ wih[0:512] + bih + bhh ----------------
__global__ __launch_bounds__(256) void k_embproj(const f16* __restrict__ emball,
    const f16* __restrict__ wih, const float* __restrict__ bih,
    const float* __restrict__ bhh, float* __restrict__ out) {
  __shared__ __align__(16) f16 sA[2][64][72], sB[2][64][72];
  int tid = threadIdx.x, lane = tid & 63, wv = tid >> 6, fr = lane & 15, fq = lane >> 4;
  int m0 = blockIdx.x * 64, n0 = blockIdx.y * 64;
  v4f acc[4] = {};
  auto src = [&](int ch, const f16*& ap, int& la, const f16*& bp, int& lb) {
    ap = emball + (size_t)m0 * 512 + ch * 64; la = 512;
    bp = wih + (size_t)(ch * 64) * 2048 + n0; lb = 2048;
  };
  gemm_db(8, src, sA, sB, tid, fr, fq, wv, acc);
  int col = n0 + wv * 16 + fr;
  float bv = bih[col] + bhh[col];
  #pragma unroll
  for (int mt = 0; mt < 4; mt++)
    #pragma unroll
    for (int r = 0; r < 4; r++)
      out[(size_t)(m0 + mt * 16 + fq * 4 + r) * 2048 + col] = acc[mt][r] + bv;
}

// ---------------- persistent time-loop kernel ----------------
struct LP {
  const f16* inh; const f16* encproj; const float* att_w; const float* att_b;
  const f16* daw; const float* bd; const f16* avw; const float* ba;
  const f16* whh; const f16* wih2; const float* embpj; const int* lens;
  float* aout;   // [2][64][4608] split-K partials of h @ [Wd|Wa|whh]
  f16* xg; float* part;
  float* h; float* c; f16* hh; f16* hseq; float* probs;
  unsigned* arrive; unsigned* go;
};

__global__ __launch_bounds__(256) void k_loop(LP P) {
  __shared__ __align__(16) char smem[4 * 64 * 72 * 2];   // 36864 B
  f16 (*sA)[64][72] = (f16(*)[64][72])smem;
  f16 (*sB)[64][72] = (f16(*)[64][72])(smem + 2 * 64 * 72 * 2);
  int tid = threadIdx.x, lane = tid & 63, wv = tid >> 6;
  int fr = lane & 15, fq = lane >> 4;
  int blk = blockIdx.x;
  unsigned bno = 0;

  for (int t = 0; t < TM_; t++) {
    // ---- Phase A: h @ [Wd | Wa | whh], split-K=2 ----
    if (blk < 144) {
      int z = (blk >= 72) ? 1 : 0, nt = blk - z * 72;
      int n0 = nt * 64;
      const f16* W; int ldb, bo;
      if (n0 < 512)       { W = P.daw; ldb = 512;  bo = n0; }
      else if (n0 < 2560) { W = P.avw; ldb = 2048; bo = n0 - 512; }
      else                { W = P.whh; ldb = 2048; bo = n0 - 2560; }
      v4f acc[4] = {};
      auto src = [&](int ch, const f16*& ap, int& la, const f16*& bp, int& lb) {
        int kl = z * 256 + ch * 64;
        ap = P.hh + kl; la = 512;
        bp = W + (size_t)kl * ldb + bo; lb = ldb;
      };
      gemm_db(4, src, sA, sB, tid, fr, fq, wv, acc);
      float* ao = P.aout + (size_t)z * 64 * 4608;
      int col = n0 + wv * 16 + fr;
      #pragma unroll
      for (int mt = 0; mt < 4; mt++)
        #pragma unroll
        for (int r = 0; r < 4; r++) {
          int b = mt * 16 + fq * 4 + r;
          ao[(size_t)b * 4608 + col] = acc[mt][r];
        }
    }
    gsync(P.arrive, P.go, ++bno);

    // ---- Phase B: attention + xg (4 blocks per batch) ----
    {
      float* sd = (float*)smem;
      float* sw = sd + 512;
      float* ss = sw + 512;
      float* sp = ss + 64;
      int b = blk >> 2, q = blk & 3;
      const float* a0 = P.aout + (size_t)b * 4608;
      const float* a1 = a0 + (size_t)64 * 4608;
      for (int i = tid; i < 512; i += 256) {
        sd[i] = a0[i] + a1[i] + P.bd[i];
        sw[i] = P.att_w[i];
      }
      __syncthreads();
      for (int l = wv; l < L_; l += 4) {
        const f16* ep = P.encproj + ((size_t)(b * L_ + l)) * 512;
        float p = 0.f;
        #pragma unroll
        for (int j = 0; j < 8; j++) {
          int A0 = lane + j * 64;
          float v = (float)ep[A0] + sd[A0];
          p = fmaf(fmaxf(v, 0.f), sw[A0], p);
        }
        #pragma unroll
        for (int off = 32; off > 0; off >>= 1) p += __shfl_xor(p, off);
        if (lane == 0) ss[l] = p;
      }
      __syncthreads();
      if (wv == 0) {
        float v = (lane < L_) ? (ss[lane] + P.att_b[0]) : -3.0e38f;
        float m = v;
        #pragma unroll
        for (int off = 32; off > 0; off >>= 1) m = fmaxf(m, __shfl_xor(m, off));
        float e = (lane < L_) ? __expf(v - m) : 0.f;
        float s = e;
        #pragma unroll
        for (int off = 32; off > 0; off >>= 1) s += __shfl_xor(s, off);
        float pr = e / s;
        if (lane < L_) {
          sp[lane] = pr;
          if (q == 0) {
            bool act = t < (P.lens[b] - 1);
            P.probs[((size_t)b * TM_ + t) * L_ + lane] = act ? pr : 0.f;
          }
        }
      }
      __syncthreads();
      int e = q * 512 + tid * 2;
      const f16* ip = P.inh + (size_t)b * L_ * ENC_ + e;
      float av0 = 0.f, av1 = 0.f;
      for (int l = 0; l < L_; l++) {
        v2h x = *(const v2h*)(ip + (size_t)l * ENC_);
        float pl = sp[l];
        av0 = fmaf(pl, (float)x[0], av0);
        av1 = fmaf(pl, (float)x[1], av1);
      }
      float g0 = sigmoidf_(a0[512 + e]     + a1[512 + e]     + P.ba[e]);
      float g1 = sigmoidf_(a0[512 + e + 1] + a1[512 + e + 1] + P.ba[e + 1]);
      v2h o; o[0] = (f16)(av0 * g0); o[1] = (f16)(av1 * g1);
      *(v2h*)(P.xg + (size_t)b * 2048 + e) = o;
    }
    gsync(P.arrive, P.go, ++bno);

    // ---- Phase C: xg @ wih[512:2560], split-K=8 ----
    {
      int n0 = (blk & 31) * 64, z = blk >> 5;
      v4f acc[4] = {};
      auto src = [&](int ch, const f16*& ap, int& la, const f16*& bp, int& lb) {
        int kl = z * 256 + ch * 64;
        ap = P.xg + kl; la = 2048;
        bp = P.wih2 + (size_t)kl * 2048 + n0; lb = 2048;
      };
      gemm_db(4, src, sA, sB, tid, fr, fq, wv, acc);
      int col = n0 + wv * 16 + fr;
      float* pp = P.part + ((size_t)z * 64) * 2048;
      #pragma unroll
      for (int mt = 0; mt < 4; mt++)
        #pragma unroll
        for (int r = 0; r < 4; r++) {
          int b = mt * 16 + fq * 4 + r;
          pp[(size_t)b * 2048 + col] = acc[mt][r];
        }
    }
    gsync(P.arrive, P.go, ++bno);

    // ---- Phase D: reduce + LSTM cell ----
    if (blk < 128) {
      int b = blk >> 1;
      int d = (blk & 1) * 256 + tid;
      const float* a0 = P.aout + (size_t)b * 4608 + 2560;
      const float* a1 = a0 + (size_t)64 * 4608;
      float g[4];
      #pragma unroll
      for (int qq = 0; qq < 4; qq++) {
        int n = qq * 512 + d;
        float s = P.embpj[((size_t)(t * 64 + b)) * 2048 + n] + a0[n] + a1[n];
        #pragma unroll
        for (int z = 0; z < KS_; z++) s += P.part[((size_t)(z * 64 + b)) * 2048 + n];
        g[qq] = s;
      }
      float i_ = sigmoidf_(g[0]);
      float f_ = sigmoidf_(g[1]);
      float gg = tanhf_(g[2]);
      float o_ = sigmoidf_(g[3]);
      float cold = P.c[b * 512 + d], hold = P.h[b * 512 + d];
      float cn = f_ * cold + i_ * gg;
      float hn = o_ * tanhf_(cn);
      bool act = t < (P.lens[b] - 1);
      float ho = act ? hn : hold;
      float co = act ? cn : cold;
      P.h[b * 512 + d] = ho;
      P.c[b * 512 + d] = co;
      P.hh[b * 512 + d] = (f16)ho;
      P.hseq[((size_t)t * 64 + b) * 512 + d] = (f16)ho;
    }
    gsync(P.arrive, P.go, ++bno);
  }
}

// ---------------- final: preds = hseq @ fc_w + fc_b ----------------
__global__ __launch_bounds__(256) void k_fc(const f16* __restrict__ hseq,
    const f16* __restrict__ W, const float* __restrict__ bias,
    const int* __restrict__ lens, float* __restrict__ preds) {
  __shared__ __align__(16) f16 sA[2][64][72], sB[2][64][72];
  int tid = threadIdx.x, lane = tid & 63, wv = tid >> 6, fr = lane & 15, fq = lane >> 4;
  int t = blockIdx.x, n0 = blockIdx.y * 64;
  v4f acc[4] = {};
  auto src = [&](int ch, const f16*& ap, int& la, const f16*& bp, int& lb) {
    ap = hseq + ((size_t)t * 64) * 512 + ch * 64; la = 512;
    bp = W + (size_t)(ch * 64) * VP_ + n0; lb = VP_;
  };
  gemm_db(8, src, sA, sB, tid, fr, fq, wv, acc);
  int col = n0 + wv * 16 + fr;
  if (col < V_) {
    float bv = bias[col];
    #pragma unroll
    for (int mt = 0; mt < 4; mt++)
      #pragma unroll
      for (int r = 0; r < 4; r++) {
        int b = mt * 16 + fq * 4 + r;
        bool act = t < (lens[b] - 1);
        preds[((size_t)b * TM_ + t) * (size_t)V_ + col] = act ? (acc[mt][r] + bv) : 0.f;
      }
  }
}

extern "C" void kernel_launch(void* const* d_in, const int* in_sizes, int n_in,
                              void* d_out, int out_size, void* d_ws, size_t ws_size,
                              hipStream_t stream) {
  (void)in_sizes; (void)n_in; (void)out_size; (void)ws_size;
  const float* input     = (const float*)d_in[0];
  const int*   captions  = (const int*)d_in[1];
  const int*   lens      = (const int*)d_in[2];
  const float* embw      = (const float*)d_in[3];
  const float* enc_att_w = (const float*)d_in[4];
  const float* enc_att_b = (const float*)d_in[5];
  const float* dec_att_w = (const float*)d_in[6];
  const float* dec_att_b = (const float*)d_in[7];
  const float* att_w     = (const float*)d_in[8];
  const float* att_b     = (const float*)d_in[9];
  const float* h_w       = (const float*)d_in[10];
  const float* h_b       = (const float*)d_in[11];
  const float* c_w       = (const float*)d_in[12];
  const float* c_b       = (const float*)d_in[13];
  const float* actv_w    = (const float*)d_in[14];
  const float* actv_b    = (const float*)d_in[15];
  const float* wih       = (const float*)d_in[16];
  const float* whh       = (const float*)d_in[17];
  const float* bih       = (const float*)d_in[18];
  const float* bhh       = (const float*)d_in[19];
  const float* fc_w      = (const float*)d_in[20];
  const float* fc_b      = (const float*)d_in[21];

  float* preds = (float*)d_out;
  float* probs = preds + (size_t)B_ * TM_ * V_;

  char* w = (char*)d_ws;
  auto alloc = [&](size_t bytes) -> char* {
    char* p = w; w += (bytes + 255) & ~(size_t)255; return p;
  };
  f16* input_h = (f16*)alloc((size_t)6422528 * 2);
  f16* eaw_h   = (f16*)alloc((size_t)1048576 * 2);
  f16* daw_h   = (f16*)alloc((size_t)262144 * 2);
  f16* avw_h   = (f16*)alloc((size_t)1048576 * 2);
  f16* wih_h   = (f16*)alloc((size_t)5242880 * 2);
  f16* whh_h   = (f16*)alloc((size_t)1048576 * 2);
  f16* hw_h    = (f16*)alloc((size_t)1048576 * 2);
  f16* cw_h    = (f16*)alloc((size_t)1048576 * 2);
  f16* fcw_pad = (f16*)alloc((size_t)512 * VP_ * 2);
  f16* meanh   = (f16*)alloc((size_t)B_ * ENC_ * 2);
  f16* encproj = (f16*)alloc((size_t)3136 * 512 * 2);
  float* hbuf  = (float*)alloc((size_t)B_ * 512 * 4);
  float* cbuf  = (float*)alloc((size_t)B_ * 512 * 4);
  f16*   hh    = (f16*)alloc((size_t)B_ * 512 * 2);
  float* aout  = (float*)alloc((size_t)2 * 64 * 4608 * 4);
  f16*   xg    = (f16*)alloc((size_t)B_ * 2048 * 2);
  float* part  = (float*)alloc((size_t)KS_ * B_ * 2048 * 4);
  f16*   hseq  = (f16*)alloc((size_t)TM_ * B_ * 512 * 2);
  f16*   embal = (f16*)alloc((size_t)TM_ * B_ * 512 * 2);
  float* embpj = (float*)alloc((size_t)TM_ * B_ * 2048 * 4);
  unsigned* barmem = (unsigned*)alloc(4096);
  unsigned* arrive = barmem;            // [256]
  unsigned* go     = barmem + 512;      // separate cacheline region

  CastJobs J;
  J.s[0] = input;     J.d[0] = input_h; J.n4[0] = 6422528 / 4;
  J.s[1] = enc_att_w; J.d[1] = eaw_h;   J.n4[1] = 1048576 / 4;
  J.s[2] = dec_att_w; J.d[2] = daw_h;   J.n4[2] = 262144 / 4;
  J.s[3] = actv_w;    J.d[3] = avw_h;   J.n4[3] = 1048576 / 4;
  J.s[4] = wih;       J.d[4] = wih_h;   J.n4[4] = 5242880 / 4;
  J.s[5] = whh;       J.d[5] = whh_h;   J.n4[5] = 1048576 / 4;
  J.s[6] = h_w;       J.d[6] = hw_h;    J.n4[6] = 1048576 / 4;
  J.s[7] = c_w;       J.d[7] = cw_h;    J.n4[7] = 1048576 / 4;
  k_cast<<<dim3((1605632 + 255) / 256, 8), 256, 0, stream>>>(J);
  k_castpad<<<dim3((VP_ / 4 + 255) / 256, 512), 256, 0, stream>>>(fc_w, fcw_pad);

  k_mean<<<64, 256, 0, stream>>>(input_h, meanh, arrive, go);
  k_embgather<<<TM_ * B_, 128, 0, stream>>>(captions, embw, embal);
  k_h0c0<<<16, 256, 0, stream>>>(meanh, hw_h, h_b, cw_h, c_b, hbuf, cbuf, hh);
  k_ep<<<dim3(49, 8), 256, 0, stream>>>(input_h, eaw_h, enc_att_b, encproj);
  k_embproj<<<dim3(TM_, 32), 256, 0, stream>>>(embal, wih_h, bih, bhh, embpj);

  LP P;
  P.inh = input_h; P.encproj = encproj; P.att_w = att_w; P.att_b = att_b;
  P.daw = daw_h; P.bd = dec_att_b; P.avw = avw_h; P.ba = actv_b;
  P.whh = whh_h; P.wih2 = wih_h + (size_t)512 * 2048;
  P.embpj = embpj; P.lens = lens;
  P.aout = aout; P.xg = xg; P.part = part;
  P.h = hbuf; P.c = cbuf; P.hh = hh; P.hseq = hseq; P.probs = probs;
  P.arrive = arrive; P.go = go;
  k_loop<<<NBLK, 256, 0, stream>>>(P);

  k_fc<<<dim3(59, 157), 256, 0, stream>>>(hseq, fcw_pad, fc_b, lens, preds);
}

// Round 6
// 3986.311 us; speedup vs baseline: 2.5201x; 1.6692x over previous
//
#include <hip/hip_runtime.h>
#include <stdint.h>

typedef _Float16 f16;
typedef f16 v8h __attribute__((ext_vector_type(8)));
typedef f16 v4h __attribute__((ext_vector_type(4)));
typedef f16 v2h __attribute__((ext_vector_type(2)));
typedef float v4f __attribute__((ext_vector_type(4)));

#define B_   64
#define L_   49
#define ENC_ 2048
#define D_   512
#define V_   10000
#define VP_  10048
#define T_   60
#define TM_  59
#define KS_  8   // split-K for LSTM gates GEMM
#define NBLK 256
#define SPIN_MAX (1u << 21)   // bounded spin: deadlock -> wrong answer, not dead container

__device__ __forceinline__ float sigmoidf_(float x) { return 1.f / (1.f + __expf(-x)); }
__device__ __forceinline__ float tanhf_(float x) {
  float e2 = __expf(2.f * x);
  return 1.f - 2.f / (e2 + 1.f);
}

// ---- coherent (L2-bypass, sc0 sc1) accessors for cross-block dynamic data ----
__device__ __forceinline__ unsigned ld_sc_u32(const unsigned* p) {
  return __hip_atomic_load(p, __ATOMIC_RELAXED, __HIP_MEMORY_SCOPE_SYSTEM);
}
__device__ __forceinline__ void st_sc_u32(unsigned* p, unsigned v) {
  __hip_atomic_store(p, v, __ATOMIC_RELAXED, __HIP_MEMORY_SCOPE_SYSTEM);
}
__device__ __forceinline__ float ld_sc_f32(const float* p) {
  return __hip_atomic_load(p, __ATOMIC_RELAXED, __HIP_MEMORY_SCOPE_SYSTEM);
}
__device__ __forceinline__ void st_sc_f32(float* p, float v) {
  __hip_atomic_store(p, v, __ATOMIC_RELAXED, __HIP_MEMORY_SCOPE_SYSTEM);
}

// ---- fence-free grid barrier (relaxed sc polls; bounded spin) ----
// Dynamic data moves via sc0sc1 (coherent at the memory-side cache, never in L1/L2),
// so no buffer_inv/wbl2 is needed. __syncthreads() drains vmcnt before s_barrier, so
// when tid0 signals arrival every sc-store of its block is already globally visible.
__device__ __forceinline__ void gsync(unsigned* arrive, unsigned* go, unsigned epoch) {
  int tid = threadIdx.x, blk = blockIdx.x;
  __syncthreads();
  if (blk == 0) {
    if (tid > 0 && tid < NBLK) {
      unsigned n = 0;
      while (__hip_atomic_load(&arrive[tid], __ATOMIC_RELAXED, __HIP_MEMORY_SCOPE_SYSTEM) < epoch) {
        __builtin_amdgcn_s_sleep(2);
        if (++n > SPIN_MAX) break;
      }
    }
    __syncthreads();
    if (tid == 0)
      __hip_atomic_store(go, epoch, __ATOMIC_RELAXED, __HIP_MEMORY_SCOPE_SYSTEM);
  } else {
    if (tid == 0) {
      __hip_atomic_store(&arrive[blk], epoch, __ATOMIC_RELAXED, __HIP_MEMORY_SCOPE_SYSTEM);
      unsigned n = 0;
      while (__hip_atomic_load(go, __ATOMIC_RELAXED, __HIP_MEMORY_SCOPE_SYSTEM) < epoch) {
        __builtin_amdgcn_s_sleep(2);
        if (++n > SPIN_MAX) break;
      }
    }
  }
  asm volatile("" ::: "memory");
  __syncthreads();
}

// ---------------- one-shot f32 -> f16 casts (8 arrays) ----------------
struct CastJobs { const float* s[8]; f16* d[8]; int n4[8]; };
__global__ __launch_bounds__(256) void k_cast(CastJobs J) {
  int a = blockIdx.y;
  int i = blockIdx.x * 256 + threadIdx.x;
  if (i >= J.n4[a]) return;
  float4 v = ((const float4*)J.s[a])[i];
  v4h o; o[0] = (f16)v.x; o[1] = (f16)v.y; o[2] = (f16)v.z; o[3] = (f16)v.w;
  ((v4h*)J.d[a])[i] = o;
}

// fc_w cast with pad to 10048 columns (zero fill)
__global__ __launch_bounds__(256) void k_castpad(const float* __restrict__ s,
                                                 f16* __restrict__ d) {
  int r = blockIdx.y;
  int c4 = blockIdx.x * 256 + threadIdx.x;
  if (c4 >= VP_ / 4) return;
  int c = c4 * 4;
  v4h o;
  if (c + 3 < V_) {
    float4 v = *(const float4*)(s + (size_t)r * V_ + c);
    o[0] = (f16)v.x; o[1] = (f16)v.y; o[2] = (f16)v.z; o[3] = (f16)v.w;
  } else {
    #pragma unroll
    for (int j = 0; j < 4; j++)
      o[j] = (c + j < V_) ? (f16)s[(size_t)r * V_ + c + j] : (f16)0.f;
  }
  *(v4h*)(d + (size_t)r * VP_ + c) = o;
}

// ---------------- mean over L (also resets the grid barrier) ----------------
__global__ __launch_bounds__(256) void k_mean(const f16* __restrict__ inh,
                                              f16* __restrict__ meanh,
                                              unsigned* __restrict__ arrive,
                                              unsigned* __restrict__ go) {
  int b = blockIdx.x, tid = threadIdx.x;
  if (b == 0) {
    __hip_atomic_store(&arrive[tid], 0u, __ATOMIC_RELAXED, __HIP_MEMORY_SCOPE_SYSTEM);
    if (tid == 0)
      __hip_atomic_store(go, 0u, __ATOMIC_RELAXED, __HIP_MEMORY_SCOPE_SYSTEM);
  }
  for (int e = tid; e < ENC_; e += 256) {
    float s = 0.f;
    for (int l = 0; l < L_; l++) s += (float)inh[((size_t)(b * L_ + l)) * ENC_ + e];
    meanh[b * ENC_ + e] = (f16)(s * (1.f / 49.f));
  }
}

// ---------------- emb gather (all steps) ----------------
__global__ __launch_bounds__(128) void k_embgather(const int* __restrict__ captions,
    const float* __restrict__ embw, f16* __restrict__ emball) {
  int row = blockIdx.x;           // t*64 + b
  int t = row >> 6, b = row & 63;
  int cap = captions[b * T_ + t];
  int k = threadIdx.x * 4;
  float4 v = *(const float4*)(embw + (size_t)cap * 512 + k);
  v4h o; o[0] = (f16)v.x; o[1] = (f16)v.y; o[2] = (f16)v.z; o[3] = (f16)v.w;
  *(v4h*)(emball + (size_t)row * 512 + k) = o;
}

// ---------------- shared 64x64 f16 MFMA tile helpers ----------------
struct AR { uint4 x, y; };
struct BR { v4h b[4]; };

__device__ __forceinline__ AR load_a64(const f16* src, int lda, int tid) {
  int r = tid >> 2, k = (tid & 3) << 4;
  const f16* p = src + (size_t)r * lda + k;
  AR a; a.x = *(const uint4*)p; a.y = *(const uint4*)(p + 8); return a;
}
__device__ __forceinline__ AR load_a64_sc(const f16* src, int lda, int tid) {
  int r = tid >> 2, k = (tid & 3) << 4;
  const unsigned* p = (const unsigned*)(src + (size_t)r * lda + k);
  AR a;
  a.x.x = ld_sc_u32(p + 0); a.x.y = ld_sc_u32(p + 1);
  a.x.z = ld_sc_u32(p + 2); a.x.w = ld_sc_u32(p + 3);
  a.y.x = ld_sc_u32(p + 4); a.y.y = ld_sc_u32(p + 5);
  a.y.z = ld_sc_u32(p + 6); a.y.w = ld_sc_u32(p + 7);
  return a;
}
__device__ __forceinline__ void write_a64(const AR& a, f16 (*sA)[72], int tid) {
  int r = tid >> 2, k = (tid & 3) << 4;
  *(uint4*)&sA[r][k] = a.x; *(uint4*)&sA[r][k + 8] = a.y;
}
__device__ __forceinline__ BR load_b64(const f16* src, int ldb, int tid) {
  BR b;
  #pragma unroll
  for (int s = 0; s < 4; s++) {
    int slot = tid + s * 256;
    int kr = slot >> 4, nc = (slot & 15) << 2;
    b.b[s] = *(const v4h*)(src + (size_t)kr * ldb + nc);
  }
  return b;
}
__device__ __forceinline__ void write_b64(const BR& b, f16 (*sB)[72], int tid) {
  #pragma unroll
  for (int s = 0; s < 4; s++) {
    int slot = tid + s * 256;
    int kr = slot >> 4, nc = (slot & 15) << 2;
    sB[nc + 0][kr] = b.b[s][0]; sB[nc + 1][kr] = b.b[s][1];
    sB[nc + 2][kr] = b.b[s][2]; sB[nc + 3][kr] = b.b[s][3];
  }
}
__device__ __forceinline__ void mfma_tile(const f16 (*sA)[72], const f16 (*sB)[72],
                                          int fr, int fq, int wv, v4f* acc) {
  #pragma unroll
  for (int kk = 0; kk < 64; kk += 32) {
    v8h bfr = *(const v8h*)&sB[wv * 16 + fr][kk + fq * 8];
    #pragma unroll
    for (int mt = 0; mt < 4; mt++) {
      v8h afr = *(const v8h*)&sA[mt * 16 + fr][kk + fq * 8];
      acc[mt] = __builtin_amdgcn_mfma_f32_16x16x32_f16(afr, bfr, acc[mt], 0, 0, 0);
    }
  }
}

// double-buffered K loop; ASC selects coherent (sc0sc1) loads for the A matrix
template <bool ASC, typename F>
__device__ __forceinline__ void gemm_db(int nch, F srcf,
    f16 (*sA)[64][72], f16 (*sB)[64][72],
    int tid, int fr, int fq, int wv, v4f* acc) {
  const f16 *ap, *bp; int la, lb;
  srcf(0, ap, la, bp, lb);
  AR ar;
  if constexpr (ASC) ar = load_a64_sc(ap, la, tid); else ar = load_a64(ap, la, tid);
  BR br = load_b64(bp, lb, tid);
  int cur = 0;
  for (int ch = 0; ch < nch; ch++) {
    AR an = ar; BR bn = br;
    if (ch + 1 < nch) {
      srcf(ch + 1, ap, la, bp, lb);
      if constexpr (ASC) an = load_a64_sc(ap, la, tid); else an = load_a64(ap, la, tid);
      bn = load_b64(bp, lb, tid);
    }
    write_a64(ar, sA[cur], tid);
    write_b64(br, sB[cur], tid);
    __syncthreads();
    mfma_tile(sA[cur], sB[cur], fr, fq, wv, acc);
    ar = an; br = bn; cur ^= 1;
  }
}

// ---------------- h0/c0 ----------------
__global__ __launch_bounds__(256) void k_h0c0(const f16* __restrict__ meanh,
    const f16* __restrict__ hw, const float* __restrict__ hb,
    const f16* __restrict__ cw, const float* __restrict__ cb,
    float* __restrict__ h, float* __restrict__ c, f16* __restrict__ hh) {
  __shared__ __align__(16) f16 sA[2][64][72], sB[2][64][72];
  int tid = threadIdx.x, lane = tid & 63, wv = tid >> 6, fr = lane & 15, fq = lane >> 4;
  int n0 = blockIdx.x * 64;
  bool ish = n0 < 512;
  const f16* W = ish ? hw : cw;
  const float* bb = ish ? hb : cb;
  int nb = ish ? n0 : (n0 - 512);
  v4f acc[4] = {};
  auto src = [&](int ch, const f16*& ap, int& la, const f16*& bp, int& lb) {
    ap = meanh + ch * 64; la = ENC_;
    bp = W + (size_t)(ch * 64) * 512 + nb; lb = 512;
  };
  gemm_db<false>(32, src, sA, sB, tid, fr, fq, wv, acc);
  int col = nb + wv * 16 + fr;
  float bv = bb[col];
  #pragma unroll
  for (int mt = 0; mt < 4; mt++)
    #pragma unroll
    for (int r = 0; r < 4; r++) {
      int b = mt * 16 + fq * 4 + r;
      float v = acc[mt][r] + bv;
      if (ish) { h[b * 512 + col] = v; hh[b * 512 + col] = (f16)v; }
      else       c[b * 512 + col] = v;
    }
}

// ---------------- enc_proj (f16 output) ----------------
__global__ __launch_bounds__(256) void k_ep(const f16* __restrict__ inh,
    const f16* __restrict__ Wh, const float* __restrict__ bias,
    f16* __restrict__ out) {
  __shared__ __align__(16) f16 sA[2][64][72], sB[2][64][72];
  int tid = threadIdx.x, lane = tid & 63, wv = tid >> 6, fr = lane & 15, fq = lane >> 4;
  int m0 = blockIdx.x * 64, n0 = blockIdx.y * 64;
  v4f acc[4] = {};
  auto src = [&](int ch, const f16*& ap, int& la, const f16*& bp, int& lb) {
    ap = inh + (size_t)m0 * ENC_ + ch * 64; la = ENC_;
    bp = Wh + (size_t)(ch * 64) * 512 + n0; lb = 512;
  };
  gemm_db<false>(32, src, sA, sB, tid, fr, fq, wv, acc);
  int col = n0 + wv * 16 + fr;
  float bv = bias[col];
  #pragma unroll
  for (int mt = 0; mt < 4; mt++)
    #pragma unroll
    for (int r = 0; r < 4; r++)
      out[(size_t)(m0 + mt * 16 + fq * 4 + r) * 512 + col] = (f16)(acc[mt][r] + bv);
}

// ---------------- embproj = emball @ wih[0:512] + bih + bhh ----------------
__global__ __launch_bounds__(256) void k_embproj(const f16* __restrict__ emball,
    const f16* __restrict__ wih, const float* __restrict__ bih,
    const float* __restrict__ bhh, float* __restrict__ out) {
  __shared__ __align__(16) f16 sA[2][64][72], sB[2][64][72];
  int tid = threadIdx.x, lane = tid & 63, wv = tid >> 6, fr = lane & 15, fq = lane >> 4;
  int m0 = blockIdx.x * 64, n0 = blockIdx.y * 64;
  v4f acc[4] = {};
  auto src = [&](int ch, const f16*& ap, int& la, const f16*& bp, int& lb) {
    ap = emball + (size_t)m0 * 512 + ch * 64; la = 512;
    bp = wih + (size_t)(ch * 64) * 2048 + n0; lb = 2048;
  };
  gemm_db<false>(8, src, sA, sB, tid, fr, fq, wv, acc);
  int col = n0 + wv * 16 + fr;
  float bv = bih[col] + bhh[col];
  #pragma unroll
  for (int mt = 0; mt < 4; mt++)
    #pragma unroll
    for (int r = 0; r < 4; r++)
      out[(size_t)(m0 + mt * 16 + fq * 4 + r) * 2048 + col] = acc[mt][r] + bv;
}

// ---------------- persistent time-loop kernel ----------------
struct LP {
  const f16* inh; const f16* encproj; const float* att_w; const float* att_b;
  const f16* daw; const float* bd; const f16* avw; const float* ba;
  const f16* whh; const f16* wih2; const float* embpj; const int* lens;
  float* aout;   // [2][64][4608] split-K partials of h @ [Wd|Wa|whh]
  f16* xg; float* part;
  float* h; float* c; f16* hh; f16* hseq; float* probs;
  unsigned* arrive; unsigned* go;
};

__global__ __launch_bounds__(256) void k_loop(LP P) {
  __shared__ __align__(16) char smem[4 * 64 * 72 * 2];   // 36864 B
  f16 (*sA)[64][72] = (f16(*)[64][72])smem;
  f16 (*sB)[64][72] = (f16(*)[64][72])(smem + 2 * 64 * 72 * 2);
  int tid = threadIdx.x, lane = tid & 63, wv = tid >> 6;
  int fr = lane & 15, fq = lane >> 4;
  int blk = blockIdx.x;
  unsigned bno = 0;

  // D-role per-thread LSTM state lives in registers across the whole loop
  float hreg = 0.f, creg = 0.f;
  int db = 0, dd = 0, dplen = 0;
  if (blk < 128) {
    db = blk >> 1; dd = (blk & 1) * 256 + tid;
    hreg = P.h[(size_t)db * 512 + dd];
    creg = P.c[(size_t)db * 512 + dd];
    dplen = P.lens[db] - 1;
  }
  int bb_ = blk >> 2;                 // B-role batch
  int bplen = P.lens[bb_] - 1;

  for (int t = 0; t < TM_; t++) {
    // ---- Phase A: h @ [Wd | Wa | whh], split-K=2 (A-matrix = hh via sc) ----
    if (blk < 144) {
      int z = (blk >= 72) ? 1 : 0, nt = blk - z * 72;
      int n0 = nt * 64;
      const f16* W; int ldb, bo;
      if (n0 < 512)       { W = P.daw; ldb = 512;  bo = n0; }
      else if (n0 < 2560) { W = P.avw; ldb = 2048; bo = n0 - 512; }
      else                { W = P.whh; ldb = 2048; bo = n0 - 2560; }
      v4f acc[4] = {};
      auto src = [&](int ch, const f16*& ap, int& la, const f16*& bp, int& lb) {
        int kl = z * 256 + ch * 64;
        ap = P.hh + kl; la = 512;
        bp = W + (size_t)kl * ldb + bo; lb = ldb;
      };
      gemm_db<true>(4, src, sA, sB, tid, fr, fq, wv, acc);
      float* ao = P.aout + (size_t)z * 64 * 4608;
      int col = n0 + wv * 16 + fr;
      #pragma unroll
      for (int mt = 0; mt < 4; mt++)
        #pragma unroll
        for (int r = 0; r < 4; r++) {
          int b = mt * 16 + fq * 4 + r;
          st_sc_f32(&ao[(size_t)b * 4608 + col], acc[mt][r]);
        }
    }
    gsync(P.arrive, P.go, ++bno);

    // ---- Phase B: attention + xg (4 blocks per batch) ----
    {
      float* sd = (float*)smem;
      float* sw = sd + 512;
      float* ss = sw + 512;
      float* sp = ss + 64;
      int b = bb_, q = blk & 3;
      const float* a0 = P.aout + (size_t)b * 4608;
      const float* a1 = a0 + (size_t)64 * 4608;
      for (int i = tid; i < 512; i += 256) {
        sd[i] = ld_sc_f32(a0 + i) + ld_sc_f32(a1 + i) + P.bd[i];
        sw[i] = P.att_w[i];
      }
      __syncthreads();
      for (int l = wv; l < L_; l += 4) {
        const f16* ep = P.encproj + ((size_t)(b * L_ + l)) * 512;
        float p = 0.f;
        #pragma unroll
        for (int j = 0; j < 8; j++) {
          int A0 = lane + j * 64;
          float v = (float)ep[A0] + sd[A0];
          p = fmaf(fmaxf(v, 0.f), sw[A0], p);
        }
        #pragma unroll
        for (int off = 32; off > 0; off >>= 1) p += __shfl_xor(p, off);
        if (lane == 0) ss[l] = p;
      }
      __syncthreads();
      if (wv == 0) {
        float v = (lane < L_) ? (ss[lane] + P.att_b[0]) : -3.0e38f;
        float m = v;
        #pragma unroll
        for (int off = 32; off > 0; off >>= 1) m = fmaxf(m, __shfl_xor(m, off));
        float e = (lane < L_) ? __expf(v - m) : 0.f;
        float s = e;
        #pragma unroll
        for (int off = 32; off > 0; off >>= 1) s += __shfl_xor(s, off);
        float pr = e / s;
        if (lane < L_) {
          sp[lane] = pr;
          if (q == 0) {
            bool act = t < bplen;
            P.probs[((size_t)b * TM_ + t) * L_ + lane] = act ? pr : 0.f;
          }
        }
      }
      __syncthreads();
      int e = q * 512 + tid * 2;
      const f16* ip = P.inh + (size_t)b * L_ * ENC_ + e;
      float av0 = 0.f, av1 = 0.f;
      for (int l = 0; l < L_; l++) {
        v2h x = *(const v2h*)(ip + (size_t)l * ENC_);
        float pl = sp[l];
        av0 = fmaf(pl, (float)x[0], av0);
        av1 = fmaf(pl, (float)x[1], av1);
      }
      float g0 = sigmoidf_(ld_sc_f32(a0 + 512 + e)     + ld_sc_f32(a1 + 512 + e)     + P.ba[e]);
      float g1 = sigmoidf_(ld_sc_f32(a0 + 512 + e + 1) + ld_sc_f32(a1 + 512 + e + 1) + P.ba[e + 1]);
      v2h o; o[0] = (f16)(av0 * g0); o[1] = (f16)(av1 * g1);
      unsigned ou; __builtin_memcpy(&ou, &o, 4);
      st_sc_u32((unsigned*)(P.xg + (size_t)b * 2048 + e), ou);
    }
    gsync(P.arrive, P.go, ++bno);

    // ---- Phase C: xg @ wih[512:2560], split-K=8 (A-matrix = xg via sc) ----
    {
      int n0 = (blk & 31) * 64, z = blk >> 5;
      v4f acc[4] = {};
      auto src = [&](int ch, const f16*& ap, int& la, const f16*& bp, int& lb) {
        int kl = z * 256 + ch * 64;
        ap = P.xg + kl; la = 2048;
        bp = P.wih2 + (size_t)kl * 2048 + n0; lb = 2048;
      };
      gemm_db<true>(4, src, sA, sB, tid, fr, fq, wv, acc);
      int col = n0 + wv * 16 + fr;
      float* pp = P.part + ((size_t)z * 64) * 2048;
      #pragma unroll
      for (int mt = 0; mt < 4; mt++)
        #pragma unroll
        for (int r = 0; r < 4; r++) {
          int b = mt * 16 + fq * 4 + r;
          st_sc_f32(&pp[(size_t)b * 2048 + col], acc[mt][r]);
        }
    }
    gsync(P.arrive, P.go, ++bno);

    // ---- Phase D: reduce + LSTM cell (state in registers) ----
    if (blk < 128) {
      int b = db, d = dd;
      const float* a0 = P.aout + (size_t)b * 4608 + 2560;
      const float* a1 = a0 + (size_t)64 * 4608;
      float g[4];
      #pragma unroll
      for (int qq = 0; qq < 4; qq++) {
        int n = qq * 512 + d;
        float s = P.embpj[((size_t)(t * 64 + b)) * 2048 + n]
                + ld_sc_f32(a0 + n) + ld_sc_f32(a1 + n);
        #pragma unroll
        for (int z = 0; z < KS_; z++)
          s += ld_sc_f32(&P.part[((size_t)(z * 64 + b)) * 2048 + n]);
        g[qq] = s;
      }
      float i_ = sigmoidf_(g[0]);
      float f_ = sigmoidf_(g[1]);
      float gg = tanhf_(g[2]);
      float o_ = sigmoidf_(g[3]);
      float cn = f_ * creg + i_ * gg;
      float hn = o_ * tanhf_(cn);
      bool act = t < dplen;
      float ho = act ? hn : hreg;
      float co = act ? cn : creg;
      hreg = ho; creg = co;
      float hop = __shfl_down(ho, 1);
      if ((tid & 1) == 0) {
        v2h hv; hv[0] = (f16)ho; hv[1] = (f16)hop;
        unsigned hu; __builtin_memcpy(&hu, &hv, 4);
        st_sc_u32((unsigned*)(P.hh + (size_t)b * 512 + d), hu);
      }
      P.hseq[((size_t)t * 64 + b) * 512 + d] = (f16)ho;
    }
    gsync(P.arrive, P.go, ++bno);
  }
}

// ---------------- final: preds = hseq @ fc_w + fc_b ----------------
__global__ __launch_bounds__(256) void k_fc(const f16* __restrict__ hseq,
    const f16* __restrict__ W, const float* __restrict__ bias,
    const int* __restrict__ lens, float* __restrict__ preds) {
  __shared__ __align__(16) f16 sA[2][64][72], sB[2][64][72];
  int tid = threadIdx.x, lane = tid & 63, wv = tid >> 6, fr = lane & 15, fq = lane >> 4;
  int t = blockIdx.x, n0 = blockIdx.y * 64;
  v4f acc[4] = {};
  auto src = [&](int ch, const f16*& ap, int& la, const f16*& bp, int& lb) {
    ap = hseq + ((size_t)t * 64) * 512 + ch * 64; la = 512;
    bp = W + (size_t)(ch * 64) * VP_ + n0; lb = VP_;
  };
  gemm_db<false>(8, src, sA, sB, tid, fr, fq, wv, acc);
  int col = n0 + wv * 16 + fr;
  if (col < V_) {
    float bv = bias[col];
    #pragma unroll
    for (int mt = 0; mt < 4; mt++)
      #pragma unroll
      for (int r = 0; r < 4; r++) {
        int b = mt * 16 + fq * 4 + r;
        bool act = t < (lens[b] - 1);
        preds[((size_t)b * TM_ + t) * (size_t)V_ + col] = act ? (acc[mt][r] + bv) : 0.f;
      }
  }
}

extern "C" void kernel_launch(void* const* d_in, const int* in_sizes, int n_in,
                              void* d_out, int out_size, void* d_ws, size_t ws_size,
                              hipStream_t stream) {
  (void)in_sizes; (void)n_in; (void)out_size; (void)ws_size;
  const float* input     = (const float*)d_in[0];
  const int*   captions  = (const int*)d_in[1];
  const int*   lens      = (const int*)d_in[2];
  const float* embw      = (const float*)d_in[3];
  const float* enc_att_w = (const float*)d_in[4];
  const float* enc_att_b = (const float*)d_in[5];
  const float* dec_att_w = (const float*)d_in[6];
  const float* dec_att_b = (const float*)d_in[7];
  const float* att_w     = (const float*)d_in[8];
  const float* att_b     = (const float*)d_in[9];
  const float* h_w       = (const float*)d_in[10];
  const float* h_b       = (const float*)d_in[11];
  const float* c_w       = (const float*)d_in[12];
  const float* c_b       = (const float*)d_in[13];
  const float* actv_w    = (const float*)d_in[14];
  const float* actv_b    = (const float*)d_in[15];
  const float* wih       = (const float*)d_in[16];
  const float* whh       = (const float*)d_in[17];
  const float* bih       = (const float*)d_in[18];
  const float* bhh       = (const float*)d_in[19];
  const float* fc_w      = (const float*)d_in[20];
  const float* fc_b      = (const float*)d_in[21];

  float* preds = (float*)d_out;
  float* probs = preds + (size_t)B_ * TM_ * V_;

  char* w = (char*)d_ws;
  auto alloc = [&](size_t bytes) -> char* {
    char* p = w; w += (bytes + 255) & ~(size_t)255; return p;
  };
  f16* input_h = (f16*)alloc((size_t)6422528 * 2);
  f16* eaw_h   = (f16*)alloc((size_t)1048576 * 2);
  f16* daw_h   = (f16*)alloc((size_t)262144 * 2);
  f16* avw_h   = (f16*)alloc((size_t)1048576 * 2);
  f16* wih_h   = (f16*)alloc((size_t)5242880 * 2);
  f16* whh_h   = (f16*)alloc((size_t)1048576 * 2);
  f16* hw_h    = (f16*)alloc((size_t)1048576 * 2);
  f16* cw_h    = (f16*)alloc((size_t)1048576 * 2);
  f16* fcw_pad = (f16*)alloc((size_t)512 * VP_ * 2);
  f16* meanh   = (f16*)alloc((size_t)B_ * ENC_ * 2);
  f16* encproj = (f16*)alloc((size_t)3136 * 512 * 2);
  float* hbuf  = (float*)alloc((size_t)B_ * 512 * 4);
  float* cbuf  = (float*)alloc((size_t)B_ * 512 * 4);
  f16*   hh    = (f16*)alloc((size_t)B_ * 512 * 2);
  float* aout  = (float*)alloc((size_t)2 * 64 * 4608 * 4);
  f16*   xg    = (f16*)alloc((size_t)B_ * 2048 * 2);
  float* part  = (float*)alloc((size_t)KS_ * B_ * 2048 * 4);
  f16*   hseq  = (f16*)alloc((size_t)TM_ * B_ * 512 * 2);
  f16*   embal = (f16*)alloc((size_t)TM_ * B_ * 512 * 2);
  float* embpj = (float*)alloc((size_t)TM_ * B_ * 2048 * 4);
  unsigned* barmem = (unsigned*)alloc(4096);
  unsigned* arrive = barmem;            // [256]
  unsigned* go     = barmem + 512;      // separate region

  CastJobs J;
  J.s[0] = input;     J.d[0] = input_h; J.n4[0] = 6422528 / 4;
  J.s[1] = enc_att_w; J.d[1] = eaw_h;   J.n4[1] = 1048576 / 4;
  J.s[2] = dec_att_w; J.d[2] = daw_h;   J.n4[2] = 262144 / 4;
  J.s[3] = actv_w;    J.d[3] = avw_h;   J.n4[3] = 1048576 / 4;
  J.s[4] = wih;       J.d[4] = wih_h;   J.n4[4] = 5242880 / 4;
  J.s[5] = whh;       J.d[5] = whh_h;   J.n4[5] = 1048576 / 4;
  J.s[6] = h_w;       J.d[6] = hw_h;    J.n4[6] = 1048576 / 4;
  J.s[7] = c_w;       J.d[7] = cw_h;    J.n4[7] = 1048576 / 4;
  k_cast<<<dim3((1605632 + 255) / 256, 8), 256, 0, stream>>>(J);
  k_castpad<<<dim3((VP_ / 4 + 255) / 256, 512), 256, 0, stream>>>(fc_w, fcw_pad);

  k_mean<<<64, 256, 0, stream>>>(input_h, meanh, arrive, go);
  k_embgather<<<TM_ * B_, 128, 0, stream>>>(captions, embw, embal);
  k_h0c0<<<16, 256, 0, stream>>>(meanh, hw_h, h_b, cw_h, c_b, hbuf, cbuf, hh);
  k_ep<<<dim3(49, 8), 256, 0, stream>>>(input_h, eaw_h, enc_att_b, encproj);
  k_embproj<<<dim3(TM_, 32), 256, 0, stream>>>(embal, wih_h, bih, bhh, embpj);

  LP P;
  P.inh = input_h; P.encproj = encproj; P.att_w = att_w; P.att_b = att_b;
  P.daw = daw_h; P.bd = dec_att_b; P.avw = avw_h; P.ba = actv_b;
  P.whh = whh_h; P.wih2 = wih_h + (size_t)512 * 2048;
  P.embpj = embpj; P.lens = lens;
  P.aout = aout; P.xg = xg; P.part = part;
  P.h = hbuf; P.c = cbuf; P.hh = hh; P.hseq = hseq; P.probs = probs;
  P.arrive = arrive; P.go = go;
  k_loop<<<NBLK, 256, 0, stream>>>(P);

  k_fc<<<dim3(59, 157), 256, 0, stream>>>(hseq, fcw_pad, fc_b, lens, preds);
}

// Round 7
// 3048.160 us; speedup vs baseline: 3.2957x; 1.3078x over previous
//
#include <hip/hip_runtime.h>
#include <stdint.h>

typedef _Float16 f16;
typedef f16 v8h __attribute__((ext_vector_type(8)));
typedef f16 v4h __attribute__((ext_vector_type(4)));
typedef f16 v2h __attribute__((ext_vector_type(2)));
typedef float v4f __attribute__((ext_vector_type(4)));

#define B_   64
#define L_   49
#define ENC_ 2048
#define D_   512
#define V_   10000
#define VP_  10048
#define T_   60
#define TM_  59
#define KS_  8   // split-K for LSTM gates GEMM
#define NBLK 256
#define NREL 16
#define SPIN_MAX (1u << 21)   // bounded spin: deadlock -> wrong answer, not dead container

__device__ __forceinline__ float sigmoidf_(float x) { return 1.f / (1.f + __expf(-x)); }
__device__ __forceinline__ float tanhf_(float x) {
  float e2 = __expf(2.f * x);
  return 1.f - 2.f / (e2 + 1.f);
}

// ---- coherent (L2-bypass, sc0 sc1) accessors for cross-block dynamic data ----
__device__ __forceinline__ unsigned ld_sc_u32(const unsigned* p) {
  return __hip_atomic_load(p, __ATOMIC_RELAXED, __HIP_MEMORY_SCOPE_SYSTEM);
}
__device__ __forceinline__ void st_sc_u32(unsigned* p, unsigned v) {
  __hip_atomic_store(p, v, __ATOMIC_RELAXED, __HIP_MEMORY_SCOPE_SYSTEM);
}
__device__ __forceinline__ float ld_sc_f32(const float* p) {
  return __hip_atomic_load(p, __ATOMIC_RELAXED, __HIP_MEMORY_SCOPE_SYSTEM);
}
__device__ __forceinline__ void st_sc_f32(float* p, float v) {
  __hip_atomic_store(p, v, __ATOMIC_RELAXED, __HIP_MEMORY_SCOPE_SYSTEM);
}

// ---- fence-free grid barrier with tree release ----
// arrive: 256 packed u32 (coalesced polling by block 0's threads).
// go: 16 slots spaced 64B, stored in PARALLEL by block 0's tid<16 -> <=16 pollers
// per slot (kills the 255-reader same-address serialization seen in R6).
__device__ __forceinline__ void gsync(unsigned* arrive, unsigned* go, unsigned epoch) {
  int tid = threadIdx.x, blk = blockIdx.x;
  __syncthreads();
  if (blk == 0) {
    if (tid > 0) {
      unsigned n = 0;
      while (__hip_atomic_load(&arrive[tid], __ATOMIC_RELAXED, __HIP_MEMORY_SCOPE_SYSTEM) < epoch) {
        __builtin_amdgcn_s_sleep(2);
        if (++n > SPIN_MAX) break;
      }
    }
    __syncthreads();
    if (tid < NREL)
      __hip_atomic_store(&go[tid * 16], epoch, __ATOMIC_RELAXED, __HIP_MEMORY_SCOPE_SYSTEM);
  } else {
    if (tid == 0) {
      __hip_atomic_store(&arrive[blk], epoch, __ATOMIC_RELAXED, __HIP_MEMORY_SCOPE_SYSTEM);
      const unsigned* gs = &go[(blk & 15) * 16];
      unsigned n = 0;
      while (__hip_atomic_load(gs, __ATOMIC_RELAXED, __HIP_MEMORY_SCOPE_SYSTEM) < epoch) {
        __builtin_amdgcn_s_sleep(2);
        if (++n > SPIN_MAX) break;
      }
    }
  }
  asm volatile("" ::: "memory");
  __syncthreads();
}

// ---------------- one-shot f32 -> f16 casts (8 arrays) ----------------
struct CastJobs { const float* s[8]; f16* d[8]; int n4[8]; };
__global__ __launch_bounds__(256) void k_cast(CastJobs J) {
  int a = blockIdx.y;
  int i = blockIdx.x * 256 + threadIdx.x;
  if (i >= J.n4[a]) return;
  float4 v = ((const float4*)J.s[a])[i];
  v4h o; o[0] = (f16)v.x; o[1] = (f16)v.y; o[2] = (f16)v.z; o[3] = (f16)v.w;
  ((v4h*)J.d[a])[i] = o;
}

// fc_w cast with pad to 10048 columns (zero fill)
__global__ __launch_bounds__(256) void k_castpad(const float* __restrict__ s,
                                                 f16* __restrict__ d) {
  int r = blockIdx.y;
  int c4 = blockIdx.x * 256 + threadIdx.x;
  if (c4 >= VP_ / 4) return;
  int c = c4 * 4;
  v4h o;
  if (c + 3 < V_) {
    float4 v = *(const float4*)(s + (size_t)r * V_ + c);
    o[0] = (f16)v.x; o[1] = (f16)v.y; o[2] = (f16)v.z; o[3] = (f16)v.w;
  } else {
    #pragma unroll
    for (int j = 0; j < 4; j++)
      o[j] = (c + j < V_) ? (f16)s[(size_t)r * V_ + c + j] : (f16)0.f;
  }
  *(v4h*)(d + (size_t)r * VP_ + c) = o;
}

// ---------------- mean over L (also resets the grid barrier) ----------------
__global__ __launch_bounds__(256) void k_mean(const f16* __restrict__ inh,
                                              f16* __restrict__ meanh,
                                              unsigned* __restrict__ arrive,
                                              unsigned* __restrict__ go) {
  int b = blockIdx.x, tid = threadIdx.x;
  if (b == 0) {
    __hip_atomic_store(&arrive[tid], 0u, __ATOMIC_RELAXED, __HIP_MEMORY_SCOPE_SYSTEM);
    if (tid < NREL)
      __hip_atomic_store(&go[tid * 16], 0u, __ATOMIC_RELAXED, __HIP_MEMORY_SCOPE_SYSTEM);
  }
  for (int e = tid; e < ENC_; e += 256) {
    float s = 0.f;
    for (int l = 0; l < L_; l++) s += (float)inh[((size_t)(b * L_ + l)) * ENC_ + e];
    meanh[b * ENC_ + e] = (f16)(s * (1.f / 49.f));
  }
}

// ---------------- emb gather (all steps) ----------------
__global__ __launch_bounds__(128) void k_embgather(const int* __restrict__ captions,
    const float* __restrict__ embw, f16* __restrict__ emball) {
  int row = blockIdx.x;           // t*64 + b
  int t = row >> 6, b = row & 63;
  int cap = captions[b * T_ + t];
  int k = threadIdx.x * 4;
  float4 v = *(const float4*)(embw + (size_t)cap * 512 + k);
  v4h o; o[0] = (f16)v.x; o[1] = (f16)v.y; o[2] = (f16)v.z; o[3] = (f16)v.w;
  *(v4h*)(emball + (size_t)row * 512 + k) = o;
}

// ---------------- shared 64x64 f16 MFMA tile helpers ----------------
struct AR { uint4 x, y; };
struct BR { v4h b[4]; };

__device__ __forceinline__ AR load_a64(const f16* src, int lda, int tid) {
  int r = tid >> 2, k = (tid & 3) << 4;
  const f16* p = src + (size_t)r * lda + k;
  AR a; a.x = *(const uint4*)p; a.y = *(const uint4*)(p + 8); return a;
}
__device__ __forceinline__ AR load_a64_sc(const f16* src, int lda, int tid) {
  int r = tid >> 2, k = (tid & 3) << 4;
  const unsigned* p = (const unsigned*)(src + (size_t)r * lda + k);
  AR a;
  a.x.x = ld_sc_u32(p + 0); a.x.y = ld_sc_u32(p + 1);
  a.x.z = ld_sc_u32(p + 2); a.x.w = ld_sc_u32(p + 3);
  a.y.x = ld_sc_u32(p + 4); a.y.y = ld_sc_u32(p + 5);
  a.y.z = ld_sc_u32(p + 6); a.y.w = ld_sc_u32(p + 7);
  return a;
}
__device__ __forceinline__ void write_a64(const AR& a, f16 (*sA)[72], int tid) {
  int r = tid >> 2, k = (tid & 3) << 4;
  *(uint4*)&sA[r][k] = a.x; *(uint4*)&sA[r][k + 8] = a.y;
}
__device__ __forceinline__ BR load_b64(const f16* src, int ldb, int tid) {
  BR b;
  #pragma unroll
  for (int s = 0; s < 4; s++) {
    int slot = tid + s * 256;
    int kr = slot >> 4, nc = (slot & 15) << 2;
    b.b[s] = *(const v4h*)(src + (size_t)kr * ldb + nc);
  }
  return b;
}
__device__ __forceinline__ void write_b64(const BR& b, f16 (*sB)[72], int tid) {
  #pragma unroll
  for (int s = 0; s < 4; s++) {
    int slot = tid + s * 256;
    int kr = slot >> 4, nc = (slot & 15) << 2;
    sB[nc + 0][kr] = b.b[s][0]; sB[nc + 1][kr] = b.b[s][1];
    sB[nc + 2][kr] = b.b[s][2]; sB[nc + 3][kr] = b.b[s][3];
  }
}
__device__ __forceinline__ void mfma_tile(const f16 (*sA)[72], const f16 (*sB)[72],
                                          int fr, int fq, int wv, v4f* acc) {
  #pragma unroll
  for (int kk = 0; kk < 64; kk += 32) {
    v8h bfr = *(const v8h*)&sB[wv * 16 + fr][kk + fq * 8];
    #pragma unroll
    for (int mt = 0; mt < 4; mt++) {
      v8h afr = *(const v8h*)&sA[mt * 16 + fr][kk + fq * 8];
      acc[mt] = __builtin_amdgcn_mfma_f32_16x16x32_f16(afr, bfr, acc[mt], 0, 0, 0);
    }
  }
}

// double-buffered K loop; ASC selects coherent (sc0sc1) loads for the A matrix
template <bool ASC, typename F>
__device__ __forceinline__ void gemm_db(int nch, F srcf,
    f16 (*sA)[64][72], f16 (*sB)[64][72],
    int tid, int fr, int fq, int wv, v4f* acc) {
  const f16 *ap, *bp; int la, lb;
  srcf(0, ap, la, bp, lb);
  AR ar;
  if constexpr (ASC) ar = load_a64_sc(ap, la, tid); else ar = load_a64(ap, la, tid);
  BR br = load_b64(bp, lb, tid);
  int cur = 0;
  for (int ch = 0; ch < nch; ch++) {
    AR an = ar; BR bn = br;
    if (ch + 1 < nch) {
      srcf(ch + 1, ap, la, bp, lb);
      if constexpr (ASC) an = load_a64_sc(ap, la, tid); else an = load_a64(ap, la, tid);
      bn = load_b64(bp, lb, tid);
    }
    write_a64(ar, sA[cur], tid);
    write_b64(br, sB[cur], tid);
    __syncthreads();
    mfma_tile(sA[cur], sB[cur], fr, fq, wv, acc);
    ar = an; br = bn; cur ^= 1;
  }
}

// ---------------- h0/c0 ----------------
__global__ __launch_bounds__(256) void k_h0c0(const f16* __restrict__ meanh,
    const f16* __restrict__ hw, const float* __restrict__ hb,
    const f16* __restrict__ cw, const float* __restrict__ cb,
    float* __restrict__ h, float* __restrict__ c, f16* __restrict__ hh) {
  __shared__ __align__(16) f16 sA[2][64][72], sB[2][64][72];
  int tid = threadIdx.x, lane = tid & 63, wv = tid >> 6, fr = lane & 15, fq = lane >> 4;
  int n0 = blockIdx.x * 64;
  bool ish = n0 < 512;
  const f16* W = ish ? hw : cw;
  const float* bb = ish ? hb : cb;
  int nb = ish ? n0 : (n0 - 512);
  v4f acc[4] = {};
  auto src = [&](int ch, const f16*& ap, int& la, const f16*& bp, int& lb) {
    ap = meanh + ch * 64; la = ENC_;
    bp = W + (size_t)(ch * 64) * 512 + nb; lb = 512;
  };
  gemm_db<false>(32, src, sA, sB, tid, fr, fq, wv, acc);
  int col = nb + wv * 16 + fr;
  float bv = bb[col];
  #pragma unroll
  for (int mt = 0; mt < 4; mt++)
    #pragma unroll
    for (int r = 0; r < 4; r++) {
      int b = mt * 16 + fq * 4 + r;
      float v = acc[mt][r] + bv;
      if (ish) { h[b * 512 + col] = v; hh[b * 512 + col] = (f16)v; }
      else       c[b * 512 + col] = v;
    }
}

// ---------------- enc_proj (f16 output) ----------------
__global__ __launch_bounds__(256) void k_ep(const f16* __restrict__ inh,
    const f16* __restrict__ Wh, const float* __restrict__ bias,
    f16* __restrict__ out) {
  __shared__ __align__(16) f16 sA[2][64][72], sB[2][64][72];
  int tid = threadIdx.x, lane = tid & 63, wv = tid >> 6, fr = lane & 15, fq = lane >> 4;
  int m0 = blockIdx.x * 64, n0 = blockIdx.y * 64;
  v4f acc[4] = {};
  auto src = [&](int ch, const f16*& ap, int& la, const f16*& bp, int& lb) {
    ap = inh + (size_t)m0 * ENC_ + ch * 64; la = ENC_;
    bp = Wh + (size_t)(ch * 64) * 512 + n0; lb = 512;
  };
  gemm_db<false>(32, src, sA, sB, tid, fr, fq, wv, acc);
  int col = n0 + wv * 16 + fr;
  float bv = bias[col];
  #pragma unroll
  for (int mt = 0; mt < 4; mt++)
    #pragma unroll
    for (int r = 0; r < 4; r++)
      out[(size_t)(m0 + mt * 16 + fq * 4 + r) * 512 + col] = (f16)(acc[mt][r] + bv);
}

// ---------------- embproj = emball @ wih[0:512] + bih + bhh ----------------
__global__ __launch_bounds__(256) void k_embproj(const f16* __restrict__ emball,
    const f16* __restrict__ wih, const float* __restrict__ bih,
    const float* __restrict__ bhh, float* __restrict__ out) {
  __shared__ __align__(16) f16 sA[2][64][72], sB[2][64][72];
  int tid = threadIdx.x, lane = tid & 63, wv = tid >> 6, fr = lane & 15, fq = lane >> 4;
  int m0 = blockIdx.x * 64, n0 = blockIdx.y * 64;
  v4f acc[4] = {};
  auto src = [&](int ch, const f16*& ap, int& la, const f16*& bp, int& lb) {
    ap = emball + (size_t)m0 * 512 + ch * 64; la = 512;
    bp = wih + (size_t)(ch * 64) * 2048 + n0; lb = 2048;
  };
  gemm_db<false>(8, src, sA, sB, tid, fr, fq, wv, acc);
  int col = n0 + wv * 16 + fr;
  float bv = bih[col] + bhh[col];
  #pragma unroll
  for (int mt = 0; mt < 4; mt++)
    #pragma unroll
    for (int r = 0; r < 4; r++)
      out[(size_t)(m0 + mt * 16 + fq * 4 + r) * 2048 + col] = acc[mt][r] + bv;
}

// ---------------- persistent time-loop kernel ----------------
struct LP {
  const f16* inh; const f16* encproj; const float* att_w; const float* att_b;
  const f16* daw; const float* bd; const f16* avw; const float* ba;
  const f16* whh; const f16* wih2; const float* embpj; const int* lens;
  float* aout;   // [2][64][4608] split-K partials of h @ [Wd|Wa|whh]
  float* esc;    // [64][64] exp(score) per (b,l)
  f16* xg; float* part;
  float* h; float* c; f16* hh; f16* hseq; float* probs;
  unsigned* arrive; unsigned* go;
};

__global__ __launch_bounds__(256) void k_loop(LP P) {
  __shared__ __align__(16) char smem[4 * 64 * 72 * 2];   // 36864 B
  f16 (*sA)[64][72] = (f16(*)[64][72])smem;
  f16 (*sB)[64][72] = (f16(*)[64][72])(smem + 2 * 64 * 72 * 2);
  int tid = threadIdx.x, lane = tid & 63, wv = tid >> 6;
  int fr = lane & 15, fq = lane >> 4;
  int blk = blockIdx.x;
  unsigned bno = 0;

  // D-role per-thread LSTM state lives in registers across the whole loop
  float hreg = 0.f, creg = 0.f;
  int db = 0, dd = 0, dplen = 0;
  if (blk < 128) {
    db = blk >> 1; dd = (blk & 1) * 256 + tid;
    hreg = P.h[(size_t)db * 512 + dd];
    creg = P.c[(size_t)db * 512 + dd];
    dplen = P.lens[db] - 1;
  }
  int bb_ = blk >> 2, bq = blk & 3;   // B-role batch / quarter
  int bplen = P.lens[bb_] - 1;

  for (int t = 0; t < TM_; t++) {
    // ---- Phase A: h @ [Wd | Wa | whh], split-K=2 (A-matrix = hh via sc) ----
    if (blk < 144) {
      int z = (blk >= 72) ? 1 : 0, nt = blk - z * 72;
      int n0 = nt * 64;
      const f16* W; int ldb, bo;
      if (n0 < 512)       { W = P.daw; ldb = 512;  bo = n0; }
      else if (n0 < 2560) { W = P.avw; ldb = 2048; bo = n0 - 512; }
      else                { W = P.whh; ldb = 2048; bo = n0 - 2560; }
      v4f acc[4] = {};
      auto src = [&](int ch, const f16*& ap, int& la, const f16*& bp, int& lb) {
        int kl = z * 256 + ch * 64;
        ap = P.hh + kl; la = 512;
        bp = W + (size_t)kl * ldb + bo; lb = ldb;
      };
      gemm_db<true>(4, src, sA, sB, tid, fr, fq, wv, acc);
      float* ao = P.aout + (size_t)z * 64 * 4608;
      int col = n0 + wv * 16 + fr;
      #pragma unroll
      for (int mt = 0; mt < 4; mt++)
        #pragma unroll
        for (int r = 0; r < 4; r++) {
          int b = mt * 16 + fq * 4 + r;
          st_sc_f32(&ao[(size_t)b * 4608 + col], acc[mt][r]);
        }
    }
    gsync(P.arrive, P.go, ++bno);

    // ---- Phase B1: scores for l-subset (encproj read ONCE per step) ----
    {
      float* sd = (float*)smem;          // 512
      float* sw = sd + 512;              // 512
      int b = bb_;
      const float* a0 = P.aout + (size_t)b * 4608;
      const float* a1 = a0 + (size_t)64 * 4608;
      for (int i = tid; i < 512; i += 256) {
        sd[i] = ld_sc_f32(a0 + i) + ld_sc_f32(a1 + i) + P.bd[i];
        sw[i] = P.att_w[i];
      }
      __syncthreads();
      int l0 = bq * 13, lend = (bq == 3) ? L_ : (l0 + 13);
      float ab = P.att_b[0];
      for (int l = l0 + wv; l < lend; l += 4) {
        const f16* ep = P.encproj + ((size_t)(b * L_ + l)) * 512;
        float p = 0.f;
        #pragma unroll
        for (int j = 0; j < 8; j++) {
          int A0 = lane + j * 64;
          float v = (float)ep[A0] + sd[A0];
          p = fmaf(fmaxf(v, 0.f), sw[A0], p);
        }
        #pragma unroll
        for (int off = 32; off > 0; off >>= 1) p += __shfl_xor(p, off);
        if (lane == 0)
          st_sc_f32(&P.esc[b * 64 + l], __expf(p + ab));   // scores ~ +-0.5: max-free softmax safe
      }
    }
    gsync(P.arrive, P.go, ++bno);

    // ---- Phase B2: softmax denom + att_vec + gate + xg ----
    {
      float* sp = (float*)smem;          // 64
      int b = bb_, q = bq;
      const float* a0 = P.aout + (size_t)b * 4608;
      const float* a1 = a0 + (size_t)64 * 4608;
      if (wv == 0) {
        float e = (lane < L_) ? ld_sc_f32(&P.esc[b * 64 + lane]) : 0.f;
        float s = e;
        #pragma unroll
        for (int off = 32; off > 0; off >>= 1) s += __shfl_xor(s, off);
        float pr = e / s;
        if (lane < L_) {
          sp[lane] = pr;
          if (q == 0) {
            bool act = t < bplen;
            P.probs[((size_t)b * TM_ + t) * L_ + lane] = act ? pr : 0.f;
          }
        }
      }
      __syncthreads();
      int e = q * 512 + tid * 2;
      const f16* ip = P.inh + (size_t)b * L_ * ENC_ + e;
      float av0 = 0.f, av1 = 0.f;
      for (int l = 0; l < L_; l++) {
        v2h x = *(const v2h*)(ip + (size_t)l * ENC_);
        float pl = sp[l];
        av0 = fmaf(pl, (float)x[0], av0);
        av1 = fmaf(pl, (float)x[1], av1);
      }
      float g0 = sigmoidf_(ld_sc_f32(a0 + 512 + e)     + ld_sc_f32(a1 + 512 + e)     + P.ba[e]);
      float g1 = sigmoidf_(ld_sc_f32(a0 + 512 + e + 1) + ld_sc_f32(a1 + 512 + e + 1) + P.ba[e + 1]);
      v2h o; o[0] = (f16)(av0 * g0); o[1] = (f16)(av1 * g1);
      unsigned ou; __builtin_memcpy(&ou, &o, 4);
      st_sc_u32((unsigned*)(P.xg + (size_t)b * 2048 + e), ou);
    }
    gsync(P.arrive, P.go, ++bno);

    // ---- Phase C: xg @ wih[512:2560], split-K=8 (A-matrix = xg via sc) ----
    {
      int n0 = (blk & 31) * 64, z = blk >> 5;
      v4f acc[4] = {};
      auto src = [&](int ch, const f16*& ap, int& la, const f16*& bp, int& lb) {
        int kl = z * 256 + ch * 64;
        ap = P.xg + kl; la = 2048;
        bp = P.wih2 + (size_t)kl * 2048 + n0; lb = 2048;
      };
      gemm_db<true>(4, src, sA, sB, tid, fr, fq, wv, acc);
      int col = n0 + wv * 16 + fr;
      float* pp = P.part + ((size_t)z * 64) * 2048;
      #pragma unroll
      for (int mt = 0; mt < 4; mt++)
        #pragma unroll
        for (int r = 0; r < 4; r++) {
          int b = mt * 16 + fq * 4 + r;
          st_sc_f32(&pp[(size_t)b * 2048 + col], acc[mt][r]);
        }
    }
    gsync(P.arrive, P.go, ++bno);

    // ---- Phase D: reduce + LSTM cell (state in registers) ----
    if (blk < 128) {
      int b = db, d = dd;
      const float* a0 = P.aout + (size_t)b * 4608 + 2560;
      const float* a1 = a0 + (size_t)64 * 4608;
      float g[4];
      #pragma unroll
      for (int qq = 0; qq < 4; qq++) {
        int n = qq * 512 + d;
        float s = P.embpj[((size_t)(t * 64 + b)) * 2048 + n]
                + ld_sc_f32(a0 + n) + ld_sc_f32(a1 + n);
        #pragma unroll
        for (int z = 0; z < KS_; z++)
          s += ld_sc_f32(&P.part[((size_t)(z * 64 + b)) * 2048 + n]);
        g[qq] = s;
      }
      float i_ = sigmoidf_(g[0]);
      float f_ = sigmoidf_(g[1]);
      float gg = tanhf_(g[2]);
      float o_ = sigmoidf_(g[3]);
      float cn = f_ * creg + i_ * gg;
      float hn = o_ * tanhf_(cn);
      bool act = t < dplen;
      float ho = act ? hn : hreg;
      float co = act ? cn : creg;
      hreg = ho; creg = co;
      float hop = __shfl_down(ho, 1);
      if ((tid & 1) == 0) {
        v2h hv; hv[0] = (f16)ho; hv[1] = (f16)hop;
        unsigned hu; __builtin_memcpy(&hu, &hv, 4);
        st_sc_u32((unsigned*)(P.hh + (size_t)b * 512 + d), hu);
      }
      P.hseq[((size_t)t * 64 + b) * 512 + d] = (f16)ho;
    }
    gsync(P.arrive, P.go, ++bno);
  }
}

// ---------------- final: preds = hseq @ fc_w + fc_b ----------------
__global__ __launch_bounds__(256) void k_fc(const f16* __restrict__ hseq,
    const f16* __restrict__ W, const float* __restrict__ bias,
    const int* __restrict__ lens, float* __restrict__ preds) {
  __shared__ __align__(16) f16 sA[2][64][72], sB[2][64][72];
  int tid = threadIdx.x, lane = tid & 63, wv = tid >> 6, fr = lane & 15, fq = lane >> 4;
  int t = blockIdx.x, n0 = blockIdx.y * 64;
  v4f acc[4] = {};
  auto src = [&](int ch, const f16*& ap, int& la, const f16*& bp, int& lb) {
    ap = hseq + ((size_t)t * 64) * 512 + ch * 64; la = 512;
    bp = W + (size_t)(ch * 64) * VP_ + n0; lb = VP_;
  };
  gemm_db<false>(8, src, sA, sB, tid, fr, fq, wv, acc);
  int col = n0 + wv * 16 + fr;
  if (col < V_) {
    float bv = bias[col];
    #pragma unroll
    for (int mt = 0; mt < 4; mt++)
      #pragma unroll
      for (int r = 0; r < 4; r++) {
        int b = mt * 16 + fq * 4 + r;
        bool act = t < (lens[b] - 1);
        preds[((size_t)b * TM_ + t) * (size_t)V_ + col] = act ? (acc[mt][r] + bv) : 0.f;
      }
  }
}

extern "C" void kernel_launch(void* const* d_in, const int* in_sizes, int n_in,
                              void* d_out, int out_size, void* d_ws, size_t ws_size,
                              hipStream_t stream) {
  (void)in_sizes; (void)n_in; (void)out_size; (void)ws_size;
  const float* input     = (const float*)d_in[0];
  const int*   captions  = (const int*)d_in[1];
  const int*   lens      = (const int*)d_in[2];
  const float* embw      = (const float*)d_in[3];
  const float* enc_att_w = (const float*)d_in[4];
  const float* enc_att_b = (const float*)d_in[5];
  const float* dec_att_w = (const float*)d_in[6];
  const float* dec_att_b = (const float*)d_in[7];
  const float* att_w     = (const float*)d_in[8];
  const float* att_b     = (const float*)d_in[9];
  const float* h_w       = (const float*)d_in[10];
  const float* h_b       = (const float*)d_in[11];
  const float* c_w       = (const float*)d_in[12];
  const float* c_b       = (const float*)d_in[13];
  const float* actv_w    = (const float*)d_in[14];
  const float* actv_b    = (const float*)d_in[15];
  const float* wih       = (const float*)d_in[16];
  const float* whh       = (const float*)d_in[17];
  const float* bih       = (const float*)d_in[18];
  const float* bhh       = (const float*)d_in[19];
  const float* fc_w      = (const float*)d_in[20];
  const float* fc_b      = (const float*)d_in[21];

  float* preds = (float*)d_out;
  float* probs = preds + (size_t)B_ * TM_ * V_;

  char* w = (char*)d_ws;
  auto alloc = [&](size_t bytes) -> char* {
    char* p = w; w += (bytes + 255) & ~(size_t)255; return p;
  };
  f16* input_h = (f16*)alloc((size_t)6422528 * 2);
  f16* eaw_h   = (f16*)alloc((size_t)1048576 * 2);
  f16* daw_h   = (f16*)alloc((size_t)262144 * 2);
  f16* avw_h   = (f16*)alloc((size_t)1048576 * 2);
  f16* wih_h   = (f16*)alloc((size_t)5242880 * 2);
  f16* whh_h   = (f16*)alloc((size_t)1048576 * 2);
  f16* hw_h    = (f16*)alloc((size_t)1048576 * 2);
  f16* cw_h    = (f16*)alloc((size_t)1048576 * 2);
  f16* fcw_pad = (f16*)alloc((size_t)512 * VP_ * 2);
  f16* meanh   = (f16*)alloc((size_t)B_ * ENC_ * 2);
  f16* encproj = (f16*)alloc((size_t)3136 * 512 * 2);
  float* hbuf  = (float*)alloc((size_t)B_ * 512 * 4);
  float* cbuf  = (float*)alloc((size_t)B_ * 512 * 4);
  f16*   hh    = (f16*)alloc((size_t)B_ * 512 * 2);
  float* aout  = (float*)alloc((size_t)2 * 64 * 4608 * 4);
  float* escb  = (float*)alloc((size_t)64 * 64 * 4);
  f16*   xg    = (f16*)alloc((size_t)B_ * 2048 * 2);
  float* part  = (float*)alloc((size_t)KS_ * B_ * 2048 * 4);
  f16*   hseq  = (f16*)alloc((size_t)TM_ * B_ * 512 * 2);
  f16*   embal = (f16*)alloc((size_t)TM_ * B_ * 512 * 2);
  float* embpj = (float*)alloc((size_t)TM_ * B_ * 2048 * 4);
  unsigned* barmem = (unsigned*)alloc(4096);
  unsigned* arrive = barmem;            // [256] packed
  unsigned* go     = barmem + 256;      // 16 slots spaced 64B

  CastJobs J;
  J.s[0] = input;     J.d[0] = input_h; J.n4[0] = 6422528 / 4;
  J.s[1] = enc_att_w; J.d[1] = eaw_h;   J.n4[1] = 1048576 / 4;
  J.s[2] = dec_att_w; J.d[2] = daw_h;   J.n4[2] = 262144 / 4;
  J.s[3] = actv_w;    J.d[3] = avw_h;   J.n4[3] = 1048576 / 4;
  J.s[4] = wih;       J.d[4] = wih_h;   J.n4[4] = 5242880 / 4;
  J.s[5] = whh;       J.d[5] = whh_h;   J.n4[5] = 1048576 / 4;
  J.s[6] = h_w;       J.d[6] = hw_h;    J.n4[6] = 1048576 / 4;
  J.s[7] = c_w;       J.d[7] = cw_h;    J.n4[7] = 1048576 / 4;
  k_cast<<<dim3((1605632 + 255) / 256, 8), 256, 0, stream>>>(J);
  k_castpad<<<dim3((VP_ / 4 + 255) / 256, 512), 256, 0, stream>>>(fc_w, fcw_pad);

  k_mean<<<64, 256, 0, stream>>>(input_h, meanh, arrive, go);
  k_embgather<<<TM_ * B_, 128, 0, stream>>>(captions, embw, embal);
  k_h0c0<<<16, 256, 0, stream>>>(meanh, hw_h, h_b, cw_h, c_b, hbuf, cbuf, hh);
  k_ep<<<dim3(49, 8), 256, 0, stream>>>(input_h, eaw_h, enc_att_b, encproj);
  k_embproj<<<dim3(TM_, 32), 256, 0, stream>>>(embal, wih_h, bih, bhh, embpj);

  LP P;
  P.inh = input_h; P.encproj = encproj; P.att_w = att_w; P.att_b = att_b;
  P.daw = daw_h; P.bd = dec_att_b; P.avw = avw_h; P.ba = actv_b;
  P.whh = whh_h; P.wih2 = wih_h + (size_t)512 * 2048;
  P.embpj = embpj; P.lens = lens;
  P.aout = aout; P.esc = escb; P.xg = xg; P.part = part;
  P.h = hbuf; P.c = cbuf; P.hh = hh; P.hseq = hseq; P.probs = probs;
  P.arrive = arrive; P.go = go;
  k_loop<<<NBLK, 256, 0, stream>>>(P);

  k_fc<<<dim3(59, 157), 256, 0, stream>>>(hseq, fcw_pad, fc_b, lens, preds);
}